// Round 8
// baseline (11395.934 us; speedup 1.0000x reference)
//
#include <hip/hip_runtime.h>
#include <math.h>

typedef __attribute__((ext_vector_type(4))) float f32x4;
typedef __attribute__((ext_vector_type(2))) float f32x2;
typedef __attribute__((ext_vector_type(8))) __bf16 bf16x8;
typedef __attribute__((ext_vector_type(4))) __bf16 bf16x4;
typedef __attribute__((ext_vector_type(4))) unsigned int u32x4;

#define DI __device__ __forceinline__

constexpr int Bd = 2, Sd = 2048, Vd = 32000, Ed = 512, Hd = 1024, MDd = 256, Pd = 4096, Wd = 128;
constexpr int BS = Bd * Sd;          // 4096 rows
constexpr int GBLK = 256;            // GRU blocks: 128 per batch group

DI float sigmoidf_(float x) { return 1.0f / (1.0f + expf(-x)); }

// ---------------------------------------------------------------------------
// Generic GEMM: C[M,N] = epi( A[M,K] * Wt[N,K]^T + bias )
// EPI 0: C = acc + bias
// EPI 1: C = (relu(acc + bias))^2
// EPI 3: atomicAdd(C[r, untied[c]], acc + (1 + gate[r]*ms) * bias[c])
// ---------------------------------------------------------------------------
template<int EPI>
__global__ __launch_bounds__(256) void gemm_bt(
    const float* __restrict__ A, const float* __restrict__ Wt,
    const float* __restrict__ bias, float* __restrict__ C,
    int M, int N, int K, int ldc,
    const float* __restrict__ gate, const float* __restrict__ msp,
    const int* __restrict__ untied)
{
  __shared__ __bf16 As[128][40];   // +8 pad: 80B row stride, 16B-aligned
  __shared__ __bf16 Bs[128][40];
  const int tid  = threadIdx.x;
  const int lane = tid & 63, wv = tid >> 6;
  const int m0 = blockIdx.y * 128, n0 = blockIdx.x * 128;
  const int wrow = (wv >> 1) * 64, wcol = (wv & 1) * 64;

  f32x4 acc[4][4] = {};

  const int sr  = tid >> 3;          // 0..31
  const int sc4 = (tid & 7) << 2;    // 0..28 step 4
  const int nk  = K >> 5;

  for (int kt = 0; kt < nk; ++kt) {
    const int k0 = kt << 5;
    __syncthreads();
    #pragma unroll
    for (int i = 0; i < 4; ++i) {
      const int r = sr + 32 * i;
      f32x4 av = *reinterpret_cast<const f32x4*>(A  + (size_t)(m0 + r) * K + k0 + sc4);
      f32x4 bv = *reinterpret_cast<const f32x4*>(Wt + (size_t)(n0 + r) * K + k0 + sc4);
      bf16x4 ah, bh;
      ah.x = (__bf16)av.x; ah.y = (__bf16)av.y; ah.z = (__bf16)av.z; ah.w = (__bf16)av.w;
      bh.x = (__bf16)bv.x; bh.y = (__bf16)bv.y; bh.z = (__bf16)bv.z; bh.w = (__bf16)bv.w;
      *reinterpret_cast<bf16x4*>(&As[r][sc4]) = ah;
      *reinterpret_cast<bf16x4*>(&Bs[r][sc4]) = bh;
    }
    __syncthreads();

    bf16x8 af[4], bfr[4];
    #pragma unroll
    for (int t2 = 0; t2 < 4; ++t2) {
      af[t2]  = *reinterpret_cast<const bf16x8*>(&As[wrow + t2 * 16 + (lane & 15)][(lane >> 4) * 8]);
      bfr[t2] = *reinterpret_cast<const bf16x8*>(&Bs[wcol + t2 * 16 + (lane & 15)][(lane >> 4) * 8]);
    }
    #pragma unroll
    for (int mi = 0; mi < 4; ++mi)
      #pragma unroll
      for (int ni = 0; ni < 4; ++ni)
        acc[mi][ni] = __builtin_amdgcn_mfma_f32_16x16x32_bf16(af[mi], bfr[ni], acc[mi][ni], 0, 0, 0);
  }

  const float ms = (EPI == 3) ? msp[0] : 0.f;
  #pragma unroll
  for (int mi = 0; mi < 4; ++mi) {
    #pragma unroll
    for (int ni = 0; ni < 4; ++ni) {
      const int cc = n0 + wcol + ni * 16 + (lane & 15);
      const float bv = bias ? bias[cc] : 0.f;
      #pragma unroll
      for (int rg = 0; rg < 4; ++rg) {
        const int rr = m0 + wrow + mi * 16 + (lane >> 4) * 4 + rg;
        const float v = acc[mi][ni][rg];
        if (EPI == 0) {
          C[(size_t)rr * ldc + cc] = v + bv;
        } else if (EPI == 1) {
          float u = fmaxf(v + bv, 0.f);
          C[(size_t)rr * ldc + cc] = u * u;
        } else {
          float g = 1.f + gate[rr] * ms;
          atomicAdd(&C[(size_t)rr * ldc + untied[cc]], v + g * bv);
        }
      }
    }
  }
}

// Device-coherent 16B poll of 4 packed u32 {val|tag3} slots. sc0 (L1 bypass)
// + sc1 (L2 bypass) reads the coherence point where producers' relaxed agent
// atomic stores land.
DI void poll4u32(const unsigned int* p, u32x4& a) {
  asm volatile("global_load_dwordx4 %0, %1, off sc0 sc1\n\t"
               "s_waitcnt vmcnt(0)"
               : "=&v"(a) : "v"(p) : "memory");
}

// ---------------------------------------------------------------------------
// Persistent GRU v8: 256 blocks x 512 threads, two independent groups of 128
// (one per batch). Wave wv of group-block gb owns ONE h-index j = gb*8+wv;
// 3 w_hh rows in registers. Exchange slots are u32 with step-tag in the 3
// mantissa LSBs ((bits&~7)|((t+1)&7)) -> poll payload is HALF of v7: 256
// pollers x one 16B sc0+sc1 load cover all 1024 slots. Tag safety: a slot is
// rewritten by the same producer thread every 2 steps (same-address stores
// from one thread stay ordered), so the only observable stale tag is
// current-2 mod 8 != current. hsm is double-buffered (read t&1, write
// (t+1)&1) making the single per-step barrier provably race-free.
// Bounded poll + 32-bit atomic-load fallback guarantees progress.
// ---------------------------------------------------------------------------
__global__ __launch_bounds__(512) void gru_kernel(
    const float* __restrict__ gi,    // [BS][3H]
    const float* __restrict__ w_hh,  // [3H][H]
    const float* __restrict__ b_hh,  // [3H]
    float* __restrict__ states,      // [BS][H]
    unsigned int* __restrict__ hb)   // [2 parity][2 batch][Hd] packed u32
{
  __shared__ float hsm[2][Hd];       // double-buffered h(t) per batch
  __shared__ float gpre_sm[2][24];   // parity-buffered pregates for 8 h-idx
  const int bid = blockIdx.x, tid = threadIdx.x;
  const int lane = tid & 63, wv = tid >> 6;
  const int b  = bid >> 7;           // batch group
  const int gb = bid & 127;          // block index within group
  const int j  = gb * 8 + wv;        // this wave's h index

  // --- w_hh rows (r,z,n for j) into registers, lane-sliced (16 floats ea) ---
  f32x4 wr[4], wz[4], wn[4];
  #pragma unroll
  for (int c = 0; c < 4; ++c) {
    const int k = lane * 4 + c * 256;
    wr[c] = *reinterpret_cast<const f32x4*>(w_hh + (size_t)(0 * Hd + j) * Hd + k);
    wz[c] = *reinterpret_cast<const f32x4*>(w_hh + (size_t)(1 * Hd + j) * Hd + k);
    wn[c] = *reinterpret_cast<const f32x4*>(w_hh + (size_t)(2 * Hd + j) * Hd + k);
  }
  const float br = b_hh[j], bz = b_hh[Hd + j], bn = b_hh[2 * Hd + j];

  for (int i = tid; i < Hd; i += 512) hsm[0][i] = 0.f;
  if (tid < 24) {
    const int g = tid >> 3, o = tid & 7;
    gpre_sm[0][tid] = gi[(size_t)b * Sd * 3 * Hd + g * Hd + gb * 8 + o];
  }
  __syncthreads();

  const int slot0 = tid * 4;         // poller's 4 slots (tid < 256)
  const bool writer = (gb == 0);

  for (int t = 0; t < Sd; ++t) {
    const int cur = t & 1, nxt = (t + 1) & 1;

    // ---- matvec: 3 dot-1024 per wave, weights in regs, h from LDS ----
    float d0 = 0, d1 = 0, d2 = 0;
    #pragma unroll
    for (int c = 0; c < 4; ++c) {
      f32x4 hv = *reinterpret_cast<const f32x4*>(&hsm[cur][lane * 4 + c * 256]);
      d0 += wr[c].x*hv.x + wr[c].y*hv.y + wr[c].z*hv.z + wr[c].w*hv.w;
      d1 += wz[c].x*hv.x + wz[c].y*hv.y + wz[c].z*hv.z + wz[c].w*hv.w;
      d2 += wn[c].x*hv.x + wn[c].y*hv.y + wn[c].z*hv.z + wn[c].w*hv.w;
    }
    #pragma unroll
    for (int off = 32; off > 0; off >>= 1) {
      d0 += __shfl_xor(d0, off, 64);
      d1 += __shfl_xor(d1, off, 64);
      d2 += __shfl_xor(d2, off, 64);
    }

    const unsigned tag3 = (unsigned)(t + 1) & 7u;
    unsigned int* hbp = hb + ((size_t)nxt * 2 + b) * Hd;

    // ---- gate: wave-parallel (lanes 0/1 sigmoids concurrent, tanh bcast) ----
    const float pgr = gpre_sm[cur][wv];
    const float pgz = gpre_sm[cur][8 + wv];
    const float pgn = gpre_sm[cur][16 + wv];
    const float a  = (lane == 0) ? (pgr + d0 + br) : (pgz + d1 + bz);
    const float sg = sigmoidf_(a);
    const float r  = __shfl(sg, 0, 64);
    const float z  = __shfl(sg, 1, 64);
    const float n  = tanhf(pgn + r * (d2 + bn));
    const float ho = hsm[cur][j];
    const float h  = (1.f - z) * n + z * ho;
    if (lane == 0) {
      const unsigned hu = (__float_as_uint(h) & ~7u) | tag3;
      __hip_atomic_store(&hbp[j], hu, __ATOMIC_RELAXED, __HIP_MEMORY_SCOPE_AGENT);
    }

    // ---- coalesced gi prefetch for t+1 into the other parity buffer ----
    if (tid < 24) {
      const int g = tid >> 3, o = tid & 7;
      const int tn = (t + 1 < Sd) ? (t + 1) : t;
      gpre_sm[nxt][tid] = gi[((size_t)b * Sd + tn) * 3 * Hd + g * Hd + gb * 8 + o];
    }

    if (tid < 256 && (t + 1 < Sd || writer)) {
      // ---- poll own-batch slots: one 16B device-coherent load per poller ----
      u32x4 a4;
      bool done = false;
      for (int rounds = 0; rounds < 32768 && !done; ++rounds) {
        poll4u32(&hbp[slot0], a4);
        if ((a4[0] & 7u) == tag3 && (a4[1] & 7u) == tag3 &&
            (a4[2] & 7u) == tag3 && (a4[3] & 7u) == tag3) {
          done = true;
        } else if (rounds >= 6) {
          __builtin_amdgcn_s_sleep(1);   // pace stragglers
        }
      }
      if (!done) {
        // guaranteed-progress fallback: 32-bit atomic loads
        bool f[4] = {false, false, false, false};
        do {
          #pragma unroll
          for (int q = 0; q < 4; ++q) {
            if (!f[q]) {
              unsigned x = __hip_atomic_load(&hbp[slot0 + q], __ATOMIC_RELAXED, __HIP_MEMORY_SCOPE_AGENT);
              if ((x & 7u) == tag3) { a4[q] = x; f[q] = true; }
            }
          }
        } while (!(f[0] && f[1] && f[2] && f[3]));
      }
      f32x4 hv4;
      hv4.x = __uint_as_float(a4[0]); hv4.y = __uint_as_float(a4[1]);
      hv4.z = __uint_as_float(a4[2]); hv4.w = __uint_as_float(a4[3]);
      *reinterpret_cast<f32x4*>(&hsm[nxt][slot0]) = hv4;
      if (writer)
        *reinterpret_cast<f32x4*>(states + ((size_t)b * Sd + t) * Hd + slot0) = hv4;
    }
    __syncthreads();   // hsm[nxt] + gpre_sm[nxt] ready before next step
  }
}

// ---------------------------------------------------------------------------
__global__ __launch_bounds__(128) void embed_kernel(
    const int* __restrict__ ids, const float* __restrict__ emb, float* __restrict__ x)
{
  const int row = blockIdx.x;
  const int tok = ids[row];
  reinterpret_cast<f32x4*>(x)[(size_t)row * (Ed / 4) + threadIdx.x] =
      reinterpret_cast<const f32x4*>(emb)[(size_t)tok * (Ed / 4) + threadIdx.x];
}

__global__ __launch_bounds__(256) void gate_kernel(
    const float* __restrict__ states, const float* __restrict__ wg,
    const float* __restrict__ bg, float* __restrict__ gate)
{
  const int row = blockIdx.x * 4 + (threadIdx.x >> 6);
  const int lane = threadIdx.x & 63;
  float s = 0;
  for (int k = lane; k < Hd; k += 64) s += states[(size_t)row * Hd + k] * wg[k];
  #pragma unroll
  for (int off = 32; off > 0; off >>= 1) s += __shfl_down(s, off, 64);
  if (lane == 0) gate[row] = sigmoidf_(s + bg[0]);
}

__global__ __launch_bounds__(256) void attn_kernel(
    const float* __restrict__ q, const float* __restrict__ k,
    const float* __restrict__ v, float* __restrict__ ctx)
{
  const int row = blockIdx.x;
  const int b = row >> 11, qi = row & (Sd - 1);
  const int tid = threadIdx.x, lane = tid & 63, wv = tid >> 6;
  __shared__ float qs[MDd];
  __shared__ float sc[Wd];
  qs[tid] = q[(size_t)row * MDd + tid];
  __syncthreads();
  const int lo = (qi > Wd) ? (qi - Wd) : 0;
  const int len = qi - lo;
  for (int jj = wv; jj < len; jj += 4) {
    const float* kr = k + (size_t)(b * Sd + lo + jj) * MDd;
    f32x4 kv = *reinterpret_cast<const f32x4*>(kr + lane * 4);
    f32x4 qv = *reinterpret_cast<const f32x4*>(&qs[lane * 4]);
    float s = kv.x * qv.x + kv.y * qv.y + kv.z * qv.z + kv.w * qv.w;
    #pragma unroll
    for (int off = 32; off > 0; off >>= 1) s += __shfl_down(s, off, 64);
    if (lane == 0) sc[jj] = s * 0.0625f;
  }
  __syncthreads();
  if (wv == 0 && len > 0) {
    float m = -3.4e38f;
    for (int jj = lane; jj < len; jj += 64) m = fmaxf(m, sc[jj]);
    #pragma unroll
    for (int off = 32; off > 0; off >>= 1) m = fmaxf(m, __shfl_xor(m, off, 64));
    float ssum = 0;
    for (int jj = lane; jj < len; jj += 64) { float e = expf(sc[jj] - m); sc[jj] = e; ssum += e; }
    #pragma unroll
    for (int off = 32; off > 0; off >>= 1) ssum += __shfl_xor(ssum, off, 64);
    const float inv = 1.f / ssum;
    for (int jj = lane; jj < len; jj += 64) sc[jj] *= inv;
  }
  __syncthreads();
  #pragma unroll
  for (int e0 = 0; e0 < Ed; e0 += 256) {
    const int e = e0 + tid;
    float a = 0;
    for (int jj = 0; jj < len; ++jj)
      a += sc[jj] * v[(size_t)(b * Sd + lo + jj) * Ed + e];
    ctx[(size_t)row * Ed + e] = a;
  }
}

__global__ __launch_bounds__(256) void fuse_kernel(
    float* __restrict__ bf, const float* __restrict__ ctx,
    const float* __restrict__ gate, const float* __restrict__ msp)
{
  const size_t i = (size_t)blockIdx.x * 256 + threadIdx.x;
  const int r = (int)(i >> 9);
  bf[i] += gate[r] * msp[0] * ctx[i];
}

// ---------------------------------------------------------------------------
extern "C" void kernel_launch(void* const* d_in, const int* in_sizes, int n_in,
                              void* d_out, int out_size, void* d_ws, size_t ws_size,
                              hipStream_t stream)
{
  const int*   ids    = (const int*)d_in[0];
  const int*   untied = (const int*)d_in[1];
  const float* emb    = (const float*)d_in[2];
  const float* w_ih   = (const float*)d_in[3];
  const float* w_hh   = (const float*)d_in[4];
  const float* b_ih   = (const float*)d_in[5];
  const float* b_hh   = (const float*)d_in[6];
  const float* wq     = (const float*)d_in[7];
  const float* bq     = (const float*)d_in[8];
  const float* wk     = (const float*)d_in[9];
  const float* bk     = (const float*)d_in[10];
  const float* wv     = (const float*)d_in[11];
  const float* bv     = (const float*)d_in[12];
  const float* wg     = (const float*)d_in[13];
  const float* bg     = (const float*)d_in[14];
  const float* w_fc   = (const float*)d_in[15];
  const float* b_fc   = (const float*)d_in[16];
  const float* w_hp   = (const float*)d_in[17];
  const float* b_hp   = (const float*)d_in[18];
  const float* out_b  = (const float*)d_in[19];
  const float* w_ph   = (const float*)d_in[20];
  const float* b_ph   = (const float*)d_in[21];
  const float* msc    = (const float*)d_in[22];
  float* out = (float*)d_out;

  float* ws      = (float*)d_ws;
  float* gi      = ws;                               // [BS][3H]
  float* states  = gi + (size_t)BS * 3 * Hd;         // [BS][H]
  float* featb   = states + (size_t)BS * Hd;         // x, then base_feat [BS][E]
  float* hfb     = featb + (size_t)BS * Ed;          // hf [BS][4E], later q/k/v/ctx/gate
  unsigned int* hb = (unsigned int*)(hfb + (size_t)BS * 4 * Ed); // [2][2][Hd] u32

  float* qb    = hfb;
  float* kb    = qb + (size_t)BS * MDd;
  float* vb    = kb + (size_t)BS * MDd;
  float* ctxb  = vb + (size_t)BS * Ed;
  float* gateb = ctxb + (size_t)BS * Ed;

  hipMemsetAsync(hb, 0, 2 * 2 * Hd * sizeof(unsigned int), stream);

  // x = emb[ids]
  embed_kernel<<<BS, 128, 0, stream>>>(ids, emb, featb);
  // gi = x @ w_ih^T + b_ih
  gemm_bt<0><<<dim3(3 * Hd / 128, BS / 128), 256, 0, stream>>>(
      featb, w_ih, b_ih, gi, BS, 3 * Hd, Ed, 3 * Hd, nullptr, nullptr, nullptr);
  // states = GRU(gi)
  gru_kernel<<<GBLK, 512, 0, stream>>>(gi, w_hh, b_hh, states, hb);
  // hf = relu(states @ w_fc^T + b_fc)^2
  gemm_bt<1><<<dim3(4 * Ed / 128, BS / 128), 256, 0, stream>>>(
      states, w_fc, b_fc, hfb, BS, 4 * Ed, Hd, 4 * Ed, nullptr, nullptr, nullptr);
  // base_feat = hf @ w_hp^T + b_hp
  gemm_bt<0><<<dim3(Ed / 128, BS / 128), 256, 0, stream>>>(
      hfb, w_hp, b_hp, featb, BS, Ed, 4 * Ed, Ed, nullptr, nullptr, nullptr);
  // base_logits = base_feat @ emb^T + out_bias  -> d_out
  gemm_bt<0><<<dim3(Vd / 128, BS / 128), 256, 0, stream>>>(
      featb, emb, out_b, out, BS, Vd, Ed, Vd, nullptr, nullptr, nullptr);
  // q,k,v
  gemm_bt<0><<<dim3(MDd / 128, BS / 128), 256, 0, stream>>>(
      states, wq, bq, qb, BS, MDd, Hd, MDd, nullptr, nullptr, nullptr);
  gemm_bt<0><<<dim3(MDd / 128, BS / 128), 256, 0, stream>>>(
      states, wk, bk, kb, BS, MDd, Hd, MDd, nullptr, nullptr, nullptr);
  gemm_bt<0><<<dim3(Ed / 128, BS / 128), 256, 0, stream>>>(
      states, wv, bv, vb, BS, Ed, Hd, Ed, nullptr, nullptr, nullptr);
  // gate
  gate_kernel<<<BS / 4, 256, 0, stream>>>(states, wg, bg, gateb);
  // ctx = windowed attention
  attn_kernel<<<BS, 256, 0, stream>>>(qb, kb, vb, ctxb);
  // base_feat += gate * ms * ctx   (in place)
  fuse_kernel<<<(BS * Ed) / 256, 256, 0, stream>>>(featb, ctxb, gateb, msc);
  // scatter: d_out[r, untied[c]] += fused_feat @ w_ph^T + (1+gate*ms)*b_ph
  gemm_bt<3><<<dim3(Pd / 128, BS / 128), 256, 0, stream>>>(
      featb, w_ph, b_ph, out, BS, Pd, Ed, Vd, gateb, msc, untied);
}

// Round 9
// 11375.703 us; speedup vs baseline: 1.0018x; 1.0018x over previous
//
#include <hip/hip_runtime.h>
#include <math.h>

typedef __attribute__((ext_vector_type(4))) float f32x4;
typedef __attribute__((ext_vector_type(2))) float f32x2;
typedef __attribute__((ext_vector_type(8))) __bf16 bf16x8;
typedef __attribute__((ext_vector_type(4))) __bf16 bf16x4;
typedef __attribute__((ext_vector_type(4))) unsigned int u32x4;

#define DI __device__ __forceinline__

constexpr int Bd = 2, Sd = 2048, Vd = 32000, Ed = 512, Hd = 1024, MDd = 256, Pd = 4096, Wd = 128;
constexpr int BS = Bd * Sd;          // 4096 rows
constexpr int GBLK = 256;            // GRU blocks: 128 per batch group

DI float sigmoidf_(float x) { return 1.0f / (1.0f + expf(-x)); }

// ---------------------------------------------------------------------------
// Generic GEMM: C[M,N] = epi( A[M,K] * Wt[N,K]^T + bias )
// EPI 0: C = acc + bias
// EPI 1: C = (relu(acc + bias))^2
// EPI 3: atomicAdd(C[r, untied[c]], acc + (1 + gate[r]*ms) * bias[c])
// ---------------------------------------------------------------------------
template<int EPI>
__global__ __launch_bounds__(256) void gemm_bt(
    const float* __restrict__ A, const float* __restrict__ Wt,
    const float* __restrict__ bias, float* __restrict__ C,
    int M, int N, int K, int ldc,
    const float* __restrict__ gate, const float* __restrict__ msp,
    const int* __restrict__ untied)
{
  __shared__ __bf16 As[128][40];   // +8 pad: 80B row stride, 16B-aligned
  __shared__ __bf16 Bs[128][40];
  const int tid  = threadIdx.x;
  const int lane = tid & 63, wv = tid >> 6;
  const int m0 = blockIdx.y * 128, n0 = blockIdx.x * 128;
  const int wrow = (wv >> 1) * 64, wcol = (wv & 1) * 64;

  f32x4 acc[4][4] = {};

  const int sr  = tid >> 3;          // 0..31
  const int sc4 = (tid & 7) << 2;    // 0..28 step 4
  const int nk  = K >> 5;

  for (int kt = 0; kt < nk; ++kt) {
    const int k0 = kt << 5;
    __syncthreads();
    #pragma unroll
    for (int i = 0; i < 4; ++i) {
      const int r = sr + 32 * i;
      f32x4 av = *reinterpret_cast<const f32x4*>(A  + (size_t)(m0 + r) * K + k0 + sc4);
      f32x4 bv = *reinterpret_cast<const f32x4*>(Wt + (size_t)(n0 + r) * K + k0 + sc4);
      bf16x4 ah, bh;
      ah.x = (__bf16)av.x; ah.y = (__bf16)av.y; ah.z = (__bf16)av.z; ah.w = (__bf16)av.w;
      bh.x = (__bf16)bv.x; bh.y = (__bf16)bv.y; bh.z = (__bf16)bv.z; bh.w = (__bf16)bv.w;
      *reinterpret_cast<bf16x4*>(&As[r][sc4]) = ah;
      *reinterpret_cast<bf16x4*>(&Bs[r][sc4]) = bh;
    }
    __syncthreads();

    bf16x8 af[4], bfr[4];
    #pragma unroll
    for (int t2 = 0; t2 < 4; ++t2) {
      af[t2]  = *reinterpret_cast<const bf16x8*>(&As[wrow + t2 * 16 + (lane & 15)][(lane >> 4) * 8]);
      bfr[t2] = *reinterpret_cast<const bf16x8*>(&Bs[wcol + t2 * 16 + (lane & 15)][(lane >> 4) * 8]);
    }
    #pragma unroll
    for (int mi = 0; mi < 4; ++mi)
      #pragma unroll
      for (int ni = 0; ni < 4; ++ni)
        acc[mi][ni] = __builtin_amdgcn_mfma_f32_16x16x32_bf16(af[mi], bfr[ni], acc[mi][ni], 0, 0, 0);
  }

  const float ms = (EPI == 3) ? msp[0] : 0.f;
  #pragma unroll
  for (int mi = 0; mi < 4; ++mi) {
    #pragma unroll
    for (int ni = 0; ni < 4; ++ni) {
      const int cc = n0 + wcol + ni * 16 + (lane & 15);
      const float bv = bias ? bias[cc] : 0.f;
      #pragma unroll
      for (int rg = 0; rg < 4; ++rg) {
        const int rr = m0 + wrow + mi * 16 + (lane >> 4) * 4 + rg;
        const float v = acc[mi][ni][rg];
        if (EPI == 0) {
          C[(size_t)rr * ldc + cc] = v + bv;
        } else if (EPI == 1) {
          float u = fmaxf(v + bv, 0.f);
          C[(size_t)rr * ldc + cc] = u * u;
        } else {
          float g = 1.f + gate[rr] * ms;
          atomicAdd(&C[(size_t)rr * ldc + untied[cc]], v + g * bv);
        }
      }
    }
  }
}

// ---------------------------------------------------------------------------
// Persistent GRU v9 = v7 + 2-deep software-pipelined device-coherent poll.
// 256 blocks x 512 threads, two independent groups of 128 (one per batch).
// Wave wv of group-block gb owns ONE h-index j = gb*8+wv; its 3 w_hh rows
// live in registers. Gate nonlinearity wave-parallel; gi pregates loaded
// coalesced into parity-buffered LDS; one barrier per step; states written
// coalesced by writer block gb==0.
// Poll: one 16B sc0+sc1 load ALWAYS in flight (issue B; vmcnt(1) -> A done;
// check A; issue A'; vmcnt(1) -> B done; check B). vmcnt(1) is correct even
// with extra outstanding stores/gi loads: everything except the just-issued
// op has retired. Detect granularity ~RTT/2 vs v7's serial RTT. First
// sample issued BEFORE gate math so its flight overlaps publish. In-flight
// register hazard closed by vmcnt(0) drain + keep-alive asm before reuse.
// Bounded rounds + atomic-load fallback guarantee progress.
// ---------------------------------------------------------------------------
__global__ __launch_bounds__(512) void gru_kernel(
    const float* __restrict__ gi,    // [BS][3H]
    const float* __restrict__ w_hh,  // [3H][H]
    const float* __restrict__ b_hh,  // [3H]
    float* __restrict__ states,      // [BS][H]
    unsigned long long* __restrict__ hb)  // [2 parity][2 batch][Hd] {tag,val}
{
  __shared__ float hsm[Hd];          // this batch's h(t-1)
  __shared__ float gpre_sm[2][24];   // parity-buffered pregates for 8 h-idx
  const int bid = blockIdx.x, tid = threadIdx.x;
  const int lane = tid & 63, wv = tid >> 6;
  const int b  = bid >> 7;           // batch group
  const int gb = bid & 127;          // block index within group
  const int j  = gb * 8 + wv;        // this wave's h index

  // --- w_hh rows (r,z,n for j) into registers, lane-sliced (16 floats ea) ---
  f32x4 wr[4], wz[4], wn[4];
  #pragma unroll
  for (int c = 0; c < 4; ++c) {
    const int k = lane * 4 + c * 256;
    wr[c] = *reinterpret_cast<const f32x4*>(w_hh + (size_t)(0 * Hd + j) * Hd + k);
    wz[c] = *reinterpret_cast<const f32x4*>(w_hh + (size_t)(1 * Hd + j) * Hd + k);
    wn[c] = *reinterpret_cast<const f32x4*>(w_hh + (size_t)(2 * Hd + j) * Hd + k);
  }
  const float br = b_hh[j], bz = b_hh[Hd + j], bn = b_hh[2 * Hd + j];

  for (int i = tid; i < Hd; i += 512) hsm[i] = 0.f;
  if (tid < 24) {
    const int g = tid >> 3, o = tid & 7;
    gpre_sm[0][tid] = gi[(size_t)b * Sd * 3 * Hd + g * Hd + gb * 8 + o];
  }
  __syncthreads();

  const int slot0 = tid * 2;         // this thread's 2 poll slots in [Hd]
  const bool writer = (gb == 0);

  for (int t = 0; t < Sd; ++t) {
    // ---- matvec: 3 dot-1024 per wave, weights in regs, h from LDS ----
    float d0 = 0, d1 = 0, d2 = 0;
    #pragma unroll
    for (int c = 0; c < 4; ++c) {
      f32x4 hv = *reinterpret_cast<const f32x4*>(&hsm[lane * 4 + c * 256]);
      d0 += wr[c].x*hv.x + wr[c].y*hv.y + wr[c].z*hv.z + wr[c].w*hv.w;
      d1 += wz[c].x*hv.x + wz[c].y*hv.y + wz[c].z*hv.z + wz[c].w*hv.w;
      d2 += wn[c].x*hv.x + wn[c].y*hv.y + wn[c].z*hv.z + wn[c].w*hv.w;
    }
    #pragma unroll
    for (int off = 32; off > 0; off >>= 1) {
      d0 += __shfl_xor(d0, off, 64);
      d1 += __shfl_xor(d1, off, 64);
      d2 += __shfl_xor(d2, off, 64);
    }

    const unsigned tagu = (unsigned)(t + 1);
    const unsigned long long tag = (unsigned long long)(t + 1);
    const int par = (t + 1) & 1;
    unsigned long long* hbp = hb + ((size_t)par * 2 + b) * Hd;
    const unsigned long long* pp = hbp + slot0;
    const bool willpoll = (t + 1 < Sd) || writer;

    // ---- early-issue first poll sample (flight overlaps gate + publish) ----
    u32x4 A{}, B{};
    if (willpoll)
      asm volatile("global_load_dwordx4 %0, %1, off sc0 sc1"
                   : "=v"(A) : "v"(pp) : "memory");

    // ---- gate: wave-parallel (lanes 0/1 sigmoids concurrent, tanh bcast) ----
    const float pgr = gpre_sm[t & 1][wv];
    const float pgz = gpre_sm[t & 1][8 + wv];
    const float pgn = gpre_sm[t & 1][16 + wv];
    const float a  = (lane == 0) ? (pgr + d0 + br) : (pgz + d1 + bz);
    const float sg = sigmoidf_(a);
    const float r  = __shfl(sg, 0, 64);
    const float z  = __shfl(sg, 1, 64);
    const float n  = tanhf(pgn + r * (d2 + bn));
    const float ho = hsm[j];
    const float h  = (1.f - z) * n + z * ho;
    if (lane == 0)
      __hip_atomic_store(&hbp[j],
                         (tag << 32) | (unsigned long long)__float_as_uint(h),
                         __ATOMIC_RELAXED, __HIP_MEMORY_SCOPE_AGENT);

    // ---- coalesced gi prefetch for t+1 into the other parity buffer ----
    if (tid < 24) {
      const int g = tid >> 3, o = tid & 7;
      const int tn = (t + 1 < Sd) ? (t + 1) : t;
      gpre_sm[par][tid] = gi[((size_t)b * Sd + tn) * 3 * Hd + g * Hd + gb * 8 + o];
    }

    if (willpoll) {
      // ---- 2-deep pipelined poll: one load always in flight ----
      float v0 = 0, v1 = 0;
      bool found = false;
      for (int rounds = 0; rounds < 8192 && !found; ++rounds) {
        asm volatile("global_load_dwordx4 %0, %1, off sc0 sc1"
                     : "=v"(B) : "v"(pp) : "memory");
        asm volatile("s_waitcnt vmcnt(1)" ::: "memory");
        if (A[1] == tagu && A[3] == tagu) {
          v0 = __uint_as_float(A[0]); v1 = __uint_as_float(A[2]);
          found = true;
        } else {
          asm volatile("global_load_dwordx4 %0, %1, off sc0 sc1"
                       : "=v"(A) : "v"(pp) : "memory");
          asm volatile("s_waitcnt vmcnt(1)" ::: "memory");
          if (B[1] == tagu && B[3] == tagu) {
            v0 = __uint_as_float(B[0]); v1 = __uint_as_float(B[2]);
            found = true;
          }
        }
      }
      asm volatile("s_waitcnt vmcnt(0)" ::: "memory");  // drain in-flight loads
      asm volatile("" :: "v"(A), "v"(B));               // keep dests live to here
      if (!found) {
        // guaranteed-progress fallback: 8B atomic loads (proven path)
        bool f0 = false, f1 = false;
        do {
          unsigned long long x0, x1;
          if (!f0) x0 = __hip_atomic_load(&hbp[slot0 + 0], __ATOMIC_RELAXED, __HIP_MEMORY_SCOPE_AGENT);
          if (!f1) x1 = __hip_atomic_load(&hbp[slot0 + 1], __ATOMIC_RELAXED, __HIP_MEMORY_SCOPE_AGENT);
          if (!f0 && (x0 >> 32) == tag) { v0 = __uint_as_float((unsigned)x0); f0 = true; }
          if (!f1 && (x1 >> 32) == tag) { v1 = __uint_as_float((unsigned)x1); f1 = true; }
        } while (!(f0 && f1));
      }
      if (writer) {
        f32x2 sv; sv.x = v0; sv.y = v1;
        *reinterpret_cast<f32x2*>(states + ((size_t)b * Sd + t) * Hd + slot0) = sv;
      }
      hsm[slot0]     = v0;
      hsm[slot0 + 1] = v1;
    }
    __syncthreads();   // hsm fully updated before next matvec
  }
}

// ---------------------------------------------------------------------------
__global__ __launch_bounds__(128) void embed_kernel(
    const int* __restrict__ ids, const float* __restrict__ emb, float* __restrict__ x)
{
  const int row = blockIdx.x;
  const int tok = ids[row];
  reinterpret_cast<f32x4*>(x)[(size_t)row * (Ed / 4) + threadIdx.x] =
      reinterpret_cast<const f32x4*>(emb)[(size_t)tok * (Ed / 4) + threadIdx.x];
}

__global__ __launch_bounds__(256) void gate_kernel(
    const float* __restrict__ states, const float* __restrict__ wg,
    const float* __restrict__ bg, float* __restrict__ gate)
{
  const int row = blockIdx.x * 4 + (threadIdx.x >> 6);
  const int lane = threadIdx.x & 63;
  float s = 0;
  for (int k = lane; k < Hd; k += 64) s += states[(size_t)row * Hd + k] * wg[k];
  #pragma unroll
  for (int off = 32; off > 0; off >>= 1) s += __shfl_down(s, off, 64);
  if (lane == 0) gate[row] = sigmoidf_(s + bg[0]);
}

__global__ __launch_bounds__(256) void attn_kernel(
    const float* __restrict__ q, const float* __restrict__ k,
    const float* __restrict__ v, float* __restrict__ ctx)
{
  const int row = blockIdx.x;
  const int b = row >> 11, qi = row & (Sd - 1);
  const int tid = threadIdx.x, lane = tid & 63, wv = tid >> 6;
  __shared__ float qs[MDd];
  __shared__ float sc[Wd];
  qs[tid] = q[(size_t)row * MDd + tid];
  __syncthreads();
  const int lo = (qi > Wd) ? (qi - Wd) : 0;
  const int len = qi - lo;
  for (int jj = wv; jj < len; jj += 4) {
    const float* kr = k + (size_t)(b * Sd + lo + jj) * MDd;
    f32x4 kv = *reinterpret_cast<const f32x4*>(kr + lane * 4);
    f32x4 qv = *reinterpret_cast<const f32x4*>(&qs[lane * 4]);
    float s = kv.x * qv.x + kv.y * qv.y + kv.z * qv.z + kv.w * qv.w;
    #pragma unroll
    for (int off = 32; off > 0; off >>= 1) s += __shfl_down(s, off, 64);
    if (lane == 0) sc[jj] = s * 0.0625f;
  }
  __syncthreads();
  if (wv == 0 && len > 0) {
    float m = -3.4e38f;
    for (int jj = lane; jj < len; jj += 64) m = fmaxf(m, sc[jj]);
    #pragma unroll
    for (int off = 32; off > 0; off >>= 1) m = fmaxf(m, __shfl_xor(m, off, 64));
    float ssum = 0;
    for (int jj = lane; jj < len; jj += 64) { float e = expf(sc[jj] - m); sc[jj] = e; ssum += e; }
    #pragma unroll
    for (int off = 32; off > 0; off >>= 1) ssum += __shfl_xor(ssum, off, 64);
    const float inv = 1.f / ssum;
    for (int jj = lane; jj < len; jj += 64) sc[jj] *= inv;
  }
  __syncthreads();
  #pragma unroll
  for (int e0 = 0; e0 < Ed; e0 += 256) {
    const int e = e0 + tid;
    float a = 0;
    for (int jj = 0; jj < len; ++jj)
      a += sc[jj] * v[(size_t)(b * Sd + lo + jj) * Ed + e];
    ctx[(size_t)row * Ed + e] = a;
  }
}

__global__ __launch_bounds__(256) void fuse_kernel(
    float* __restrict__ bf, const float* __restrict__ ctx,
    const float* __restrict__ gate, const float* __restrict__ msp)
{
  const size_t i = (size_t)blockIdx.x * 256 + threadIdx.x;
  const int r = (int)(i >> 9);
  bf[i] += gate[r] * msp[0] * ctx[i];
}

// ---------------------------------------------------------------------------
extern "C" void kernel_launch(void* const* d_in, const int* in_sizes, int n_in,
                              void* d_out, int out_size, void* d_ws, size_t ws_size,
                              hipStream_t stream)
{
  const int*   ids    = (const int*)d_in[0];
  const int*   untied = (const int*)d_in[1];
  const float* emb    = (const float*)d_in[2];
  const float* w_ih   = (const float*)d_in[3];
  const float* w_hh   = (const float*)d_in[4];
  const float* b_ih   = (const float*)d_in[5];
  const float* b_hh   = (const float*)d_in[6];
  const float* wq     = (const float*)d_in[7];
  const float* bq     = (const float*)d_in[8];
  const float* wk     = (const float*)d_in[9];
  const float* bk     = (const float*)d_in[10];
  const float* wv     = (const float*)d_in[11];
  const float* bv     = (const float*)d_in[12];
  const float* wg     = (const float*)d_in[13];
  const float* bg     = (const float*)d_in[14];
  const float* w_fc   = (const float*)d_in[15];
  const float* b_fc   = (const float*)d_in[16];
  const float* w_hp   = (const float*)d_in[17];
  const float* b_hp   = (const float*)d_in[18];
  const float* out_b  = (const float*)d_in[19];
  const float* w_ph   = (const float*)d_in[20];
  const float* b_ph   = (const float*)d_in[21];
  const float* msc    = (const float*)d_in[22];
  float* out = (float*)d_out;

  float* ws      = (float*)d_ws;
  float* gi      = ws;                               // [BS][3H]
  float* states  = gi + (size_t)BS * 3 * Hd;         // [BS][H]
  float* featb   = states + (size_t)BS * Hd;         // x, then base_feat [BS][E]
  float* hfb     = featb + (size_t)BS * Ed;          // hf [BS][4E], later q/k/v/ctx/gate
  unsigned long long* hb = (unsigned long long*)(hfb + (size_t)BS * 4 * Ed); // [2][2][Hd]

  float* qb    = hfb;
  float* kb    = qb + (size_t)BS * MDd;
  float* vb    = kb + (size_t)BS * MDd;
  float* ctxb  = vb + (size_t)BS * Ed;
  float* gateb = ctxb + (size_t)BS * Ed;

  hipMemsetAsync(hb, 0, 2 * 2 * Hd * sizeof(unsigned long long), stream);

  // x = emb[ids]
  embed_kernel<<<BS, 128, 0, stream>>>(ids, emb, featb);
  // gi = x @ w_ih^T + b_ih
  gemm_bt<0><<<dim3(3 * Hd / 128, BS / 128), 256, 0, stream>>>(
      featb, w_ih, b_ih, gi, BS, 3 * Hd, Ed, 3 * Hd, nullptr, nullptr, nullptr);
  // states = GRU(gi)
  gru_kernel<<<GBLK, 512, 0, stream>>>(gi, w_hh, b_hh, states, hb);
  // hf = relu(states @ w_fc^T + b_fc)^2
  gemm_bt<1><<<dim3(4 * Ed / 128, BS / 128), 256, 0, stream>>>(
      states, w_fc, b_fc, hfb, BS, 4 * Ed, Hd, 4 * Ed, nullptr, nullptr, nullptr);
  // base_feat = hf @ w_hp^T + b_hp
  gemm_bt<0><<<dim3(Ed / 128, BS / 128), 256, 0, stream>>>(
      hfb, w_hp, b_hp, featb, BS, Ed, 4 * Ed, Ed, nullptr, nullptr, nullptr);
  // base_logits = base_feat @ emb^T + out_bias  -> d_out
  gemm_bt<0><<<dim3(Vd / 128, BS / 128), 256, 0, stream>>>(
      featb, emb, out_b, out, BS, Vd, Ed, Vd, nullptr, nullptr, nullptr);
  // q,k,v
  gemm_bt<0><<<dim3(MDd / 128, BS / 128), 256, 0, stream>>>(
      states, wq, bq, qb, BS, MDd, Hd, MDd, nullptr, nullptr, nullptr);
  gemm_bt<0><<<dim3(MDd / 128, BS / 128), 256, 0, stream>>>(
      states, wk, bk, kb, BS, MDd, Hd, MDd, nullptr, nullptr, nullptr);
  gemm_bt<0><<<dim3(Ed / 128, BS / 128), 256, 0, stream>>>(
      states, wv, bv, vb, BS, Ed, Hd, Ed, nullptr, nullptr, nullptr);
  // gate
  gate_kernel<<<BS / 4, 256, 0, stream>>>(states, wg, bg, gateb);
  // ctx = windowed attention
  attn_kernel<<<BS, 256, 0, stream>>>(qb, kb, vb, ctxb);
  // base_feat += gate * ms * ctx   (in place)
  fuse_kernel<<<(BS * Ed) / 256, 256, 0, stream>>>(featb, ctxb, gateb, msc);
  // scatter: d_out[r, untied[c]] += fused_feat @ w_ph^T + (1+gate*ms)*b_ph
  gemm_bt<3><<<dim3(Pd / 128, BS / 128), 256, 0, stream>>>(
      featb, w_ph, b_ph, out, BS, Pd, Ed, Vd, gateb, msc, untied);
}

// Round 10
// 10815.063 us; speedup vs baseline: 1.0537x; 1.0518x over previous
//
#include <hip/hip_runtime.h>
#include <math.h>

typedef __attribute__((ext_vector_type(4))) float f32x4;
typedef __attribute__((ext_vector_type(2))) float f32x2;
typedef __attribute__((ext_vector_type(8))) __bf16 bf16x8;
typedef __attribute__((ext_vector_type(4))) __bf16 bf16x4;
typedef __attribute__((ext_vector_type(4))) unsigned int u32x4;

#define DI __device__ __forceinline__

constexpr int Bd = 2, Sd = 2048, Vd = 32000, Ed = 512, Hd = 1024, MDd = 256, Pd = 4096, Wd = 128;
constexpr int BS = Bd * Sd;          // 4096 rows
constexpr int GBLK = 256;            // GRU blocks: 128 per batch group

DI float sigmoidf_(float x) { return 1.0f / (1.0f + expf(-x)); }

// ---------------------------------------------------------------------------
// Generic GEMM: C[M,N] = epi( A[M,K] * Wt[N,K]^T + bias )
// EPI 0: C = acc + bias
// EPI 1: C = (relu(acc + bias))^2
// EPI 3: atomicAdd(C[r, untied[c]], acc + (1 + gate[r]*ms) * bias[c])
// ---------------------------------------------------------------------------
template<int EPI>
__global__ __launch_bounds__(256) void gemm_bt(
    const float* __restrict__ A, const float* __restrict__ Wt,
    const float* __restrict__ bias, float* __restrict__ C,
    int M, int N, int K, int ldc,
    const float* __restrict__ gate, const float* __restrict__ msp,
    const int* __restrict__ untied)
{
  __shared__ __bf16 As[128][40];   // +8 pad: 80B row stride, 16B-aligned
  __shared__ __bf16 Bs[128][40];
  const int tid  = threadIdx.x;
  const int lane = tid & 63, wv = tid >> 6;
  const int m0 = blockIdx.y * 128, n0 = blockIdx.x * 128;
  const int wrow = (wv >> 1) * 64, wcol = (wv & 1) * 64;

  f32x4 acc[4][4] = {};

  const int sr  = tid >> 3;          // 0..31
  const int sc4 = (tid & 7) << 2;    // 0..28 step 4
  const int nk  = K >> 5;

  for (int kt = 0; kt < nk; ++kt) {
    const int k0 = kt << 5;
    __syncthreads();
    #pragma unroll
    for (int i = 0; i < 4; ++i) {
      const int r = sr + 32 * i;
      f32x4 av = *reinterpret_cast<const f32x4*>(A  + (size_t)(m0 + r) * K + k0 + sc4);
      f32x4 bv = *reinterpret_cast<const f32x4*>(Wt + (size_t)(n0 + r) * K + k0 + sc4);
      bf16x4 ah, bh;
      ah.x = (__bf16)av.x; ah.y = (__bf16)av.y; ah.z = (__bf16)av.z; ah.w = (__bf16)av.w;
      bh.x = (__bf16)bv.x; bh.y = (__bf16)bv.y; bh.z = (__bf16)bv.z; bh.w = (__bf16)bv.w;
      *reinterpret_cast<bf16x4*>(&As[r][sc4]) = ah;
      *reinterpret_cast<bf16x4*>(&Bs[r][sc4]) = bh;
    }
    __syncthreads();

    bf16x8 af[4], bfr[4];
    #pragma unroll
    for (int t2 = 0; t2 < 4; ++t2) {
      af[t2]  = *reinterpret_cast<const bf16x8*>(&As[wrow + t2 * 16 + (lane & 15)][(lane >> 4) * 8]);
      bfr[t2] = *reinterpret_cast<const bf16x8*>(&Bs[wcol + t2 * 16 + (lane & 15)][(lane >> 4) * 8]);
    }
    #pragma unroll
    for (int mi = 0; mi < 4; ++mi)
      #pragma unroll
      for (int ni = 0; ni < 4; ++ni)
        acc[mi][ni] = __builtin_amdgcn_mfma_f32_16x16x32_bf16(af[mi], bfr[ni], acc[mi][ni], 0, 0, 0);
  }

  const float ms = (EPI == 3) ? msp[0] : 0.f;
  #pragma unroll
  for (int mi = 0; mi < 4; ++mi) {
    #pragma unroll
    for (int ni = 0; ni < 4; ++ni) {
      const int cc = n0 + wcol + ni * 16 + (lane & 15);
      const float bv = bias ? bias[cc] : 0.f;
      #pragma unroll
      for (int rg = 0; rg < 4; ++rg) {
        const int rr = m0 + wrow + mi * 16 + (lane >> 4) * 4 + rg;
        const float v = acc[mi][ni][rg];
        if (EPI == 0) {
          C[(size_t)rr * ldc + cc] = v + bv;
        } else if (EPI == 1) {
          float u = fmaxf(v + bv, 0.f);
          C[(size_t)rr * ldc + cc] = u * u;
        } else {
          float g = 1.f + gate[rr] * ms;
          atomicAdd(&C[(size_t)rr * ldc + untied[cc]], v + g * bv);
        }
      }
    }
  }
}

// Device-coherent 16B poll: sc0 (L1 bypass) + sc1 (L2 bypass) reads the
// coherence point where producers' relaxed agent atomic stores land.
DI void poll2_coherent(const unsigned long long* p, u32x4& a) {
  asm volatile("global_load_dwordx4 %0, %1, off sc0 sc1\n\t"
               "s_waitcnt vmcnt(0)"
               : "=&v"(a) : "v"(p) : "memory");
}

// ---------------------------------------------------------------------------
// Persistent GRU v10 = v7 + (a) calibrated sleep-backoff poll, (b)
// __launch_bounds__(512,2) so the 12 weight f32x4 stay truly register-
// resident (v7's VGPR_Count=48 showed the allocator was re-loading them
// on the post-barrier critical path).
// 256 blocks x 512 threads, two independent groups of 128 (one per batch).
// Wave wv of group-block gb owns ONE h-index j = gb*8+wv. Gate math is
// wave-parallel; gi pregates loaded coalesced into parity-buffered LDS;
// one barrier per step; states written coalesced by writer block gb==0.
// Poll schedule: one immediate probe (catches late-skew), then s_sleep(16)
// (~0.43us: data cannot be ready sooner), then probe paced by s_sleep(4)
// (~107ns). ~2-3x fewer poll requests/step than v7 -> publishes see a
// quieter fabric. Bounded rounds + atomic-load fallback guarantee progress.
// ---------------------------------------------------------------------------
__global__ __launch_bounds__(512, 2) void gru_kernel(
    const float* __restrict__ gi,    // [BS][3H]
    const float* __restrict__ w_hh,  // [3H][H]
    const float* __restrict__ b_hh,  // [3H]
    float* __restrict__ states,      // [BS][H]
    unsigned long long* __restrict__ hb)  // [2 parity][2 batch][Hd] {tag,val}
{
  __shared__ float hsm[Hd];          // this batch's h(t-1)
  __shared__ float gpre_sm[2][24];   // parity-buffered pregates for 8 h-idx
  const int bid = blockIdx.x, tid = threadIdx.x;
  const int lane = tid & 63, wv = tid >> 6;
  const int b  = bid >> 7;           // batch group
  const int gb = bid & 127;          // block index within group
  const int j  = gb * 8 + wv;        // this wave's h index

  // --- w_hh rows (r,z,n for j) into registers, lane-sliced (16 floats ea) ---
  f32x4 wr[4], wz[4], wn[4];
  #pragma unroll
  for (int c = 0; c < 4; ++c) {
    const int k = lane * 4 + c * 256;
    wr[c] = *reinterpret_cast<const f32x4*>(w_hh + (size_t)(0 * Hd + j) * Hd + k);
    wz[c] = *reinterpret_cast<const f32x4*>(w_hh + (size_t)(1 * Hd + j) * Hd + k);
    wn[c] = *reinterpret_cast<const f32x4*>(w_hh + (size_t)(2 * Hd + j) * Hd + k);
  }
  const float br = b_hh[j], bz = b_hh[Hd + j], bn = b_hh[2 * Hd + j];

  for (int i = tid; i < Hd; i += 512) hsm[i] = 0.f;
  if (tid < 24) {
    const int g = tid >> 3, o = tid & 7;
    gpre_sm[0][tid] = gi[(size_t)b * Sd * 3 * Hd + g * Hd + gb * 8 + o];
  }
  __syncthreads();

  const int slot0 = tid * 2;         // this thread's 2 poll slots in [Hd]
  const bool writer = (gb == 0);

  for (int t = 0; t < Sd; ++t) {
    // ---- matvec: 3 dot-1024 per wave, weights in regs, h from LDS ----
    float d0 = 0, d1 = 0, d2 = 0;
    #pragma unroll
    for (int c = 0; c < 4; ++c) {
      f32x4 hv = *reinterpret_cast<const f32x4*>(&hsm[lane * 4 + c * 256]);
      d0 += wr[c].x*hv.x + wr[c].y*hv.y + wr[c].z*hv.z + wr[c].w*hv.w;
      d1 += wz[c].x*hv.x + wz[c].y*hv.y + wz[c].z*hv.z + wz[c].w*hv.w;
      d2 += wn[c].x*hv.x + wn[c].y*hv.y + wn[c].z*hv.z + wn[c].w*hv.w;
    }
    #pragma unroll
    for (int off = 32; off > 0; off >>= 1) {
      d0 += __shfl_xor(d0, off, 64);
      d1 += __shfl_xor(d1, off, 64);
      d2 += __shfl_xor(d2, off, 64);
    }

    const unsigned tagu = (unsigned)(t + 1);
    const unsigned long long tag = (unsigned long long)(t + 1);
    const int par = (t + 1) & 1;
    unsigned long long* hbp = hb + ((size_t)par * 2 + b) * Hd;

    // ---- gate: wave-parallel (lanes 0/1 sigmoids concurrent, tanh bcast) ----
    const float pgr = gpre_sm[t & 1][wv];
    const float pgz = gpre_sm[t & 1][8 + wv];
    const float pgn = gpre_sm[t & 1][16 + wv];
    const float a  = (lane == 0) ? (pgr + d0 + br) : (pgz + d1 + bz);
    const float sg = sigmoidf_(a);
    const float r  = __shfl(sg, 0, 64);
    const float z  = __shfl(sg, 1, 64);
    const float n  = tanhf(pgn + r * (d2 + bn));
    const float ho = hsm[j];
    const float h  = (1.f - z) * n + z * ho;
    if (lane == 0)
      __hip_atomic_store(&hbp[j],
                         (tag << 32) | (unsigned long long)__float_as_uint(h),
                         __ATOMIC_RELAXED, __HIP_MEMORY_SCOPE_AGENT);

    // ---- coalesced gi prefetch for t+1 into the other parity buffer ----
    if (tid < 24) {
      const int g = tid >> 3, o = tid & 7;
      const int tn = (t + 1 < Sd) ? (t + 1) : t;
      gpre_sm[par][tid] = gi[((size_t)b * Sd + tn) * 3 * Hd + g * Hd + gb * 8 + o];
    }

    if (t + 1 < Sd || writer) {
      // ---- backoff poll: 1 immediate probe, then sleep-paced probes ----
      float v0 = 0, v1 = 0;
      bool done = false;
      u32x4 a4;
      poll2_coherent(&hbp[slot0], a4);
      if (a4[1] == tagu && a4[3] == tagu) {
        v0 = __uint_as_float(a4[0]); v1 = __uint_as_float(a4[2]);
        done = true;
      } else {
        __builtin_amdgcn_s_sleep(16);          // ~0.43us: can't be ready sooner
        for (int rounds = 0; rounds < 8192 && !done; ++rounds) {
          poll2_coherent(&hbp[slot0], a4);
          if (a4[1] == tagu && a4[3] == tagu) {
            v0 = __uint_as_float(a4[0]); v1 = __uint_as_float(a4[2]);
            done = true;
          } else {
            __builtin_amdgcn_s_sleep(4);       // ~107ns pacing
          }
        }
      }
      if (!done) {
        // guaranteed-progress fallback: 8B atomic loads (proven path)
        bool f0 = false, f1 = false;
        do {
          unsigned long long x0, x1;
          if (!f0) x0 = __hip_atomic_load(&hbp[slot0 + 0], __ATOMIC_RELAXED, __HIP_MEMORY_SCOPE_AGENT);
          if (!f1) x1 = __hip_atomic_load(&hbp[slot0 + 1], __ATOMIC_RELAXED, __HIP_MEMORY_SCOPE_AGENT);
          if (!f0 && (x0 >> 32) == tag) { v0 = __uint_as_float((unsigned)x0); f0 = true; }
          if (!f1 && (x1 >> 32) == tag) { v1 = __uint_as_float((unsigned)x1); f1 = true; }
        } while (!(f0 && f1));
      }
      if (writer) {
        f32x2 sv; sv.x = v0; sv.y = v1;
        *reinterpret_cast<f32x2*>(states + ((size_t)b * Sd + t) * Hd + slot0) = sv;
      }
      hsm[slot0]     = v0;
      hsm[slot0 + 1] = v1;
    }
    __syncthreads();   // hsm fully updated before next matvec
  }
}

// ---------------------------------------------------------------------------
__global__ __launch_bounds__(128) void embed_kernel(
    const int* __restrict__ ids, const float* __restrict__ emb, float* __restrict__ x)
{
  const int row = blockIdx.x;
  const int tok = ids[row];
  reinterpret_cast<f32x4*>(x)[(size_t)row * (Ed / 4) + threadIdx.x] =
      reinterpret_cast<const f32x4*>(emb)[(size_t)tok * (Ed / 4) + threadIdx.x];
}

__global__ __launch_bounds__(256) void gate_kernel(
    const float* __restrict__ states, const float* __restrict__ wg,
    const float* __restrict__ bg, float* __restrict__ gate)
{
  const int row = blockIdx.x * 4 + (threadIdx.x >> 6);
  const int lane = threadIdx.x & 63;
  float s = 0;
  for (int k = lane; k < Hd; k += 64) s += states[(size_t)row * Hd + k] * wg[k];
  #pragma unroll
  for (int off = 32; off > 0; off >>= 1) s += __shfl_down(s, off, 64);
  if (lane == 0) gate[row] = sigmoidf_(s + bg[0]);
}

__global__ __launch_bounds__(256) void attn_kernel(
    const float* __restrict__ q, const float* __restrict__ k,
    const float* __restrict__ v, float* __restrict__ ctx)
{
  const int row = blockIdx.x;
  const int b = row >> 11, qi = row & (Sd - 1);
  const int tid = threadIdx.x, lane = tid & 63, wv = tid >> 6;
  __shared__ float qs[MDd];
  __shared__ float sc[Wd];
  qs[tid] = q[(size_t)row * MDd + tid];
  __syncthreads();
  const int lo = (qi > Wd) ? (qi - Wd) : 0;
  const int len = qi - lo;
  for (int jj = wv; jj < len; jj += 4) {
    const float* kr = k + (size_t)(b * Sd + lo + jj) * MDd;
    f32x4 kv = *reinterpret_cast<const f32x4*>(kr + lane * 4);
    f32x4 qv = *reinterpret_cast<const f32x4*>(&qs[lane * 4]);
    float s = kv.x * qv.x + kv.y * qv.y + kv.z * qv.z + kv.w * qv.w;
    #pragma unroll
    for (int off = 32; off > 0; off >>= 1) s += __shfl_down(s, off, 64);
    if (lane == 0) sc[jj] = s * 0.0625f;
  }
  __syncthreads();
  if (wv == 0 && len > 0) {
    float m = -3.4e38f;
    for (int jj = lane; jj < len; jj += 64) m = fmaxf(m, sc[jj]);
    #pragma unroll
    for (int off = 32; off > 0; off >>= 1) m = fmaxf(m, __shfl_xor(m, off, 64));
    float ssum = 0;
    for (int jj = lane; jj < len; jj += 64) { float e = expf(sc[jj] - m); sc[jj] = e; ssum += e; }
    #pragma unroll
    for (int off = 32; off > 0; off >>= 1) ssum += __shfl_xor(ssum, off, 64);
    const float inv = 1.f / ssum;
    for (int jj = lane; jj < len; jj += 64) sc[jj] *= inv;
  }
  __syncthreads();
  #pragma unroll
  for (int e0 = 0; e0 < Ed; e0 += 256) {
    const int e = e0 + tid;
    float a = 0;
    for (int jj = 0; jj < len; ++jj)
      a += sc[jj] * v[(size_t)(b * Sd + lo + jj) * Ed + e];
    ctx[(size_t)row * Ed + e] = a;
  }
}

__global__ __launch_bounds__(256) void fuse_kernel(
    float* __restrict__ bf, const float* __restrict__ ctx,
    const float* __restrict__ gate, const float* __restrict__ msp)
{
  const size_t i = (size_t)blockIdx.x * 256 + threadIdx.x;
  const int r = (int)(i >> 9);
  bf[i] += gate[r] * msp[0] * ctx[i];
}

// ---------------------------------------------------------------------------
extern "C" void kernel_launch(void* const* d_in, const int* in_sizes, int n_in,
                              void* d_out, int out_size, void* d_ws, size_t ws_size,
                              hipStream_t stream)
{
  const int*   ids    = (const int*)d_in[0];
  const int*   untied = (const int*)d_in[1];
  const float* emb    = (const float*)d_in[2];
  const float* w_ih   = (const float*)d_in[3];
  const float* w_hh   = (const float*)d_in[4];
  const float* b_ih   = (const float*)d_in[5];
  const float* b_hh   = (const float*)d_in[6];
  const float* wq     = (const float*)d_in[7];
  const float* bq     = (const float*)d_in[8];
  const float* wk     = (const float*)d_in[9];
  const float* bk     = (const float*)d_in[10];
  const float* wv     = (const float*)d_in[11];
  const float* bv     = (const float*)d_in[12];
  const float* wg     = (const float*)d_in[13];
  const float* bg     = (const float*)d_in[14];
  const float* w_fc   = (const float*)d_in[15];
  const float* b_fc   = (const float*)d_in[16];
  const float* w_hp   = (const float*)d_in[17];
  const float* b_hp   = (const float*)d_in[18];
  const float* out_b  = (const float*)d_in[19];
  const float* w_ph   = (const float*)d_in[20];
  const float* b_ph   = (const float*)d_in[21];
  const float* msc    = (const float*)d_in[22];
  float* out = (float*)d_out;

  float* ws      = (float*)d_ws;
  float* gi      = ws;                               // [BS][3H]
  float* states  = gi + (size_t)BS * 3 * Hd;         // [BS][H]
  float* featb   = states + (size_t)BS * Hd;         // x, then base_feat [BS][E]
  float* hfb     = featb + (size_t)BS * Ed;          // hf [BS][4E], later q/k/v/ctx/gate
  unsigned long long* hb = (unsigned long long*)(hfb + (size_t)BS * 4 * Ed); // [2][2][Hd]

  float* qb    = hfb;
  float* kb    = qb + (size_t)BS * MDd;
  float* vb    = kb + (size_t)BS * MDd;
  float* ctxb  = vb + (size_t)BS * Ed;
  float* gateb = ctxb + (size_t)BS * Ed;

  hipMemsetAsync(hb, 0, 2 * 2 * Hd * sizeof(unsigned long long), stream);

  // x = emb[ids]
  embed_kernel<<<BS, 128, 0, stream>>>(ids, emb, featb);
  // gi = x @ w_ih^T + b_ih
  gemm_bt<0><<<dim3(3 * Hd / 128, BS / 128), 256, 0, stream>>>(
      featb, w_ih, b_ih, gi, BS, 3 * Hd, Ed, 3 * Hd, nullptr, nullptr, nullptr);
  // states = GRU(gi)
  gru_kernel<<<GBLK, 512, 0, stream>>>(gi, w_hh, b_hh, states, hb);
  // hf = relu(states @ w_fc^T + b_fc)^2
  gemm_bt<1><<<dim3(4 * Ed / 128, BS / 128), 256, 0, stream>>>(
      states, w_fc, b_fc, hfb, BS, 4 * Ed, Hd, 4 * Ed, nullptr, nullptr, nullptr);
  // base_feat = hf @ w_hp^T + b_hp
  gemm_bt<0><<<dim3(Ed / 128, BS / 128), 256, 0, stream>>>(
      hfb, w_hp, b_hp, featb, BS, Ed, 4 * Ed, Ed, nullptr, nullptr, nullptr);
  // base_logits = base_feat @ emb^T + out_bias  -> d_out
  gemm_bt<0><<<dim3(Vd / 128, BS / 128), 256, 0, stream>>>(
      featb, emb, out_b, out, BS, Vd, Ed, Vd, nullptr, nullptr, nullptr);
  // q,k,v
  gemm_bt<0><<<dim3(MDd / 128, BS / 128), 256, 0, stream>>>(
      states, wq, bq, qb, BS, MDd, Hd, MDd, nullptr, nullptr, nullptr);
  gemm_bt<0><<<dim3(MDd / 128, BS / 128), 256, 0, stream>>>(
      states, wk, bk, kb, BS, MDd, Hd, MDd, nullptr, nullptr, nullptr);
  gemm_bt<0><<<dim3(Ed / 128, BS / 128), 256, 0, stream>>>(
      states, wv, bv, vb, BS, Ed, Hd, Ed, nullptr, nullptr, nullptr);
  // gate
  gate_kernel<<<BS / 4, 256, 0, stream>>>(states, wg, bg, gateb);
  // ctx = windowed attention
  attn_kernel<<<BS, 256, 0, stream>>>(qb, kb, vb, ctxb);
  // base_feat += gate * ms * ctx   (in place)
  fuse_kernel<<<(BS * Ed) / 256, 256, 0, stream>>>(featb, ctxb, gateb, msc);
  // scatter: d_out[r, untied[c]] += fused_feat @ w_ph^T + (1+gate*ms)*b_ph
  gemm_bt<3><<<dim3(Pd / 128, BS / 128), 256, 0, stream>>>(
      featb, w_ph, b_ph, out, BS, Pd, Ed, Vd, gateb, msc, untied);
}

// Round 11
// 9123.042 us; speedup vs baseline: 1.2491x; 1.1855x over previous
//
#include <hip/hip_runtime.h>
#include <math.h>

typedef __attribute__((ext_vector_type(4))) float f32x4;
typedef __attribute__((ext_vector_type(2))) float f32x2;
typedef __attribute__((ext_vector_type(8))) __bf16 bf16x8;
typedef __attribute__((ext_vector_type(4))) __bf16 bf16x4;
typedef __attribute__((ext_vector_type(4))) unsigned int u32x4;

#define DI __device__ __forceinline__

constexpr int Bd = 2, Sd = 2048, Vd = 32000, Ed = 512, Hd = 1024, MDd = 256, Pd = 4096, Wd = 128;
constexpr int BS = Bd * Sd;          // 4096 rows
constexpr int GBLK = 128;            // GRU blocks: 64 per batch group, 1024 thr

DI float sigmoidf_(float x) { return 1.0f / (1.0f + expf(-x)); }

// ---------------------------------------------------------------------------
// Generic GEMM: C[M,N] = epi( A[M,K] * Wt[N,K]^T + bias )
// EPI 0: C = acc + bias
// EPI 1: C = (relu(acc + bias))^2
// EPI 3: atomicAdd(C[r, untied[c]], acc + (1 + gate[r]*ms) * bias[c])
// ---------------------------------------------------------------------------
template<int EPI>
__global__ __launch_bounds__(256) void gemm_bt(
    const float* __restrict__ A, const float* __restrict__ Wt,
    const float* __restrict__ bias, float* __restrict__ C,
    int M, int N, int K, int ldc,
    const float* __restrict__ gate, const float* __restrict__ msp,
    const int* __restrict__ untied)
{
  __shared__ __bf16 As[128][40];   // +8 pad: 80B row stride, 16B-aligned
  __shared__ __bf16 Bs[128][40];
  const int tid  = threadIdx.x;
  const int lane = tid & 63, wv = tid >> 6;
  const int m0 = blockIdx.y * 128, n0 = blockIdx.x * 128;
  const int wrow = (wv >> 1) * 64, wcol = (wv & 1) * 64;

  f32x4 acc[4][4] = {};

  const int sr  = tid >> 3;          // 0..31
  const int sc4 = (tid & 7) << 2;    // 0..28 step 4
  const int nk  = K >> 5;

  for (int kt = 0; kt < nk; ++kt) {
    const int k0 = kt << 5;
    __syncthreads();
    #pragma unroll
    for (int i = 0; i < 4; ++i) {
      const int r = sr + 32 * i;
      f32x4 av = *reinterpret_cast<const f32x4*>(A  + (size_t)(m0 + r) * K + k0 + sc4);
      f32x4 bv = *reinterpret_cast<const f32x4*>(Wt + (size_t)(n0 + r) * K + k0 + sc4);
      bf16x4 ah, bh;
      ah.x = (__bf16)av.x; ah.y = (__bf16)av.y; ah.z = (__bf16)av.z; ah.w = (__bf16)av.w;
      bh.x = (__bf16)bv.x; bh.y = (__bf16)bv.y; bh.z = (__bf16)bv.z; bh.w = (__bf16)bv.w;
      *reinterpret_cast<bf16x4*>(&As[r][sc4]) = ah;
      *reinterpret_cast<bf16x4*>(&Bs[r][sc4]) = bh;
    }
    __syncthreads();

    bf16x8 af[4], bfr[4];
    #pragma unroll
    for (int t2 = 0; t2 < 4; ++t2) {
      af[t2]  = *reinterpret_cast<const bf16x8*>(&As[wrow + t2 * 16 + (lane & 15)][(lane >> 4) * 8]);
      bfr[t2] = *reinterpret_cast<const bf16x8*>(&Bs[wcol + t2 * 16 + (lane & 15)][(lane >> 4) * 8]);
    }
    #pragma unroll
    for (int mi = 0; mi < 4; ++mi)
      #pragma unroll
      for (int ni = 0; ni < 4; ++ni)
        acc[mi][ni] = __builtin_amdgcn_mfma_f32_16x16x32_bf16(af[mi], bfr[ni], acc[mi][ni], 0, 0, 0);
  }

  const float ms = (EPI == 3) ? msp[0] : 0.f;
  #pragma unroll
  for (int mi = 0; mi < 4; ++mi) {
    #pragma unroll
    for (int ni = 0; ni < 4; ++ni) {
      const int cc = n0 + wcol + ni * 16 + (lane & 15);
      const float bv = bias ? bias[cc] : 0.f;
      #pragma unroll
      for (int rg = 0; rg < 4; ++rg) {
        const int rr = m0 + wrow + mi * 16 + (lane >> 4) * 4 + rg;
        const float v = acc[mi][ni][rg];
        if (EPI == 0) {
          C[(size_t)rr * ldc + cc] = v + bv;
        } else if (EPI == 1) {
          float u = fmaxf(v + bv, 0.f);
          C[(size_t)rr * ldc + cc] = u * u;
        } else {
          float g = 1.f + gate[rr] * ms;
          atomicAdd(&C[(size_t)rr * ldc + untied[cc]], v + g * bv);
        }
      }
    }
  }
}

// Device-coherent 16B poll: sc0 (L1 bypass) + sc1 (L2 bypass) reads the
// coherence point where producers' relaxed agent atomic stores land.
DI void poll2_coherent(const unsigned long long* p, u32x4& a) {
  asm volatile("global_load_dwordx4 %0, %1, off sc0 sc1\n\t"
               "s_waitcnt vmcnt(0)"
               : "=&v"(a) : "v"(p) : "memory");
}

// ---------------------------------------------------------------------------
// Persistent GRU v11 = v7 structure with HALF the sync participants at the
// same critical path: 128 blocks x 1024 threads (16 waves), two independent
// groups of 64 (one per batch). Wave wv of group-block gb owns ONE h-index
// j = gb*16+wv (3 w_hh rows in registers, 3 dot-1024s — identical per-wave
// work to v7). 512 pollers/block x one 16B sc0+sc1 load cover all 1024
// slots; per-step straggler max is over 128 blocks (vs v7's 256) and poll
// burst halves to 1 MB/round. Per-block slot ROTATION (gb*8 slots) staggers
// the L3 bank sweep across blocks; writer blocks (gb==0) land on rotation 0
// so the coalesced states write is preserved.
// Single barrier per step is self-gating (v7 proof, unchanged for 16 waves):
// a thread overwrites hsm only after detecting ALL t+1 tags, which requires
// every wave of every block (incl. its own) to have finished its matvec
// reads. Bounded poll + atomic-load fallback guarantees progress.
// ---------------------------------------------------------------------------
__global__ __launch_bounds__(1024) void gru_kernel(
    const float* __restrict__ gi,    // [BS][3H]
    const float* __restrict__ w_hh,  // [3H][H]
    const float* __restrict__ b_hh,  // [3H]
    float* __restrict__ states,      // [BS][H]
    unsigned long long* __restrict__ hb)  // [2 parity][2 batch][Hd] {tag,val}
{
  __shared__ float hsm[Hd];          // this batch's h(t-1)
  __shared__ float gpre_sm[2][48];   // parity-buffered pregates for 16 h-idx
  const int bid = blockIdx.x, tid = threadIdx.x;
  const int lane = tid & 63, wv = tid >> 6;
  const int b  = bid >> 6;           // batch group
  const int gb = bid & 63;           // block index within group
  const int j  = gb * 16 + wv;       // this wave's h index

  // --- w_hh rows (r,z,n for j) into registers, lane-sliced (16 floats ea) ---
  f32x4 wr[4], wz[4], wn[4];
  #pragma unroll
  for (int c = 0; c < 4; ++c) {
    const int k = lane * 4 + c * 256;
    wr[c] = *reinterpret_cast<const f32x4*>(w_hh + (size_t)(0 * Hd + j) * Hd + k);
    wz[c] = *reinterpret_cast<const f32x4*>(w_hh + (size_t)(1 * Hd + j) * Hd + k);
    wn[c] = *reinterpret_cast<const f32x4*>(w_hh + (size_t)(2 * Hd + j) * Hd + k);
  }
  const float br = b_hh[j], bz = b_hh[Hd + j], bn = b_hh[2 * Hd + j];

  for (int i = tid; i < Hd; i += 1024) hsm[i] = 0.f;
  if (tid < 48) {
    const int g = tid >> 4, o = tid & 15;
    gpre_sm[0][tid] = gi[(size_t)b * Sd * 3 * Hd + g * Hd + gb * 16 + o];
  }
  __syncthreads();

  // rotated slot pair: staggers each block's L3 sweep; gb==0 -> rotation 0
  const int slot0 = (((tid & 511) + (gb << 3)) & 511) * 2;
  const bool poller = (tid < 512);
  const bool writer = (gb == 0);

  for (int t = 0; t < Sd; ++t) {
    // ---- matvec: 3 dot-1024 per wave, weights in regs, h from LDS ----
    float d0 = 0, d1 = 0, d2 = 0;
    #pragma unroll
    for (int c = 0; c < 4; ++c) {
      f32x4 hv = *reinterpret_cast<const f32x4*>(&hsm[lane * 4 + c * 256]);
      d0 += wr[c].x*hv.x + wr[c].y*hv.y + wr[c].z*hv.z + wr[c].w*hv.w;
      d1 += wz[c].x*hv.x + wz[c].y*hv.y + wz[c].z*hv.z + wz[c].w*hv.w;
      d2 += wn[c].x*hv.x + wn[c].y*hv.y + wn[c].z*hv.z + wn[c].w*hv.w;
    }
    #pragma unroll
    for (int off = 32; off > 0; off >>= 1) {
      d0 += __shfl_xor(d0, off, 64);
      d1 += __shfl_xor(d1, off, 64);
      d2 += __shfl_xor(d2, off, 64);
    }

    const unsigned tagu = (unsigned)(t + 1);
    const unsigned long long tag = (unsigned long long)(t + 1);
    const int par = (t + 1) & 1;
    unsigned long long* hbp = hb + ((size_t)par * 2 + b) * Hd;

    // ---- gate: wave-parallel (lanes 0/1 sigmoids concurrent, tanh bcast) ----
    const float pgr = gpre_sm[t & 1][wv];
    const float pgz = gpre_sm[t & 1][16 + wv];
    const float pgn = gpre_sm[t & 1][32 + wv];
    const float a  = (lane == 0) ? (pgr + d0 + br) : (pgz + d1 + bz);
    const float sg = sigmoidf_(a);
    const float r  = __shfl(sg, 0, 64);
    const float z  = __shfl(sg, 1, 64);
    const float n  = tanhf(pgn + r * (d2 + bn));
    const float ho = hsm[j];
    const float h  = (1.f - z) * n + z * ho;
    if (lane == 0)
      __hip_atomic_store(&hbp[j],
                         (tag << 32) | (unsigned long long)__float_as_uint(h),
                         __ATOMIC_RELAXED, __HIP_MEMORY_SCOPE_AGENT);

    // ---- coalesced gi prefetch for t+1 into the other parity buffer ----
    if (tid < 48) {
      const int g = tid >> 4, o = tid & 15;
      const int tn = (t + 1 < Sd) ? (t + 1) : t;
      gpre_sm[par][tid] = gi[((size_t)b * Sd + tn) * 3 * Hd + g * Hd + gb * 16 + o];
    }

    if (poller && (t + 1 < Sd || writer)) {
      // ---- poll own-batch slots: one 16B device-coherent load per poller ----
      float v0 = 0, v1 = 0;
      bool done = false;
      for (int rounds = 0; rounds < 16384 && !done; ++rounds) {
        u32x4 a4;
        poll2_coherent(&hbp[slot0], a4);
        if (a4[1] == tagu && a4[3] == tagu) {
          v0 = __uint_as_float(a4[0]); v1 = __uint_as_float(a4[2]);
          done = true;
        } else if (rounds >= 6) {
          __builtin_amdgcn_s_sleep(1);   // pace stragglers
        }
      }
      if (!done) {
        // guaranteed-progress fallback: 8B atomic loads (proven path)
        bool f0 = false, f1 = false;
        do {
          unsigned long long x0, x1;
          if (!f0) x0 = __hip_atomic_load(&hbp[slot0 + 0], __ATOMIC_RELAXED, __HIP_MEMORY_SCOPE_AGENT);
          if (!f1) x1 = __hip_atomic_load(&hbp[slot0 + 1], __ATOMIC_RELAXED, __HIP_MEMORY_SCOPE_AGENT);
          if (!f0 && (x0 >> 32) == tag) { v0 = __uint_as_float((unsigned)x0); f0 = true; }
          if (!f1 && (x1 >> 32) == tag) { v1 = __uint_as_float((unsigned)x1); f1 = true; }
        } while (!(f0 && f1));
      }
      if (writer) {
        f32x2 sv; sv.x = v0; sv.y = v1;
        *reinterpret_cast<f32x2*>(states + ((size_t)b * Sd + t) * Hd + slot0) = sv;
      }
      hsm[slot0]     = v0;
      hsm[slot0 + 1] = v1;
    }
    __syncthreads();   // hsm fully updated before next matvec
  }
}

// ---------------------------------------------------------------------------
__global__ __launch_bounds__(128) void embed_kernel(
    const int* __restrict__ ids, const float* __restrict__ emb, float* __restrict__ x)
{
  const int row = blockIdx.x;
  const int tok = ids[row];
  reinterpret_cast<f32x4*>(x)[(size_t)row * (Ed / 4) + threadIdx.x] =
      reinterpret_cast<const f32x4*>(emb)[(size_t)tok * (Ed / 4) + threadIdx.x];
}

__global__ __launch_bounds__(256) void gate_kernel(
    const float* __restrict__ states, const float* __restrict__ wg,
    const float* __restrict__ bg, float* __restrict__ gate)
{
  const int row = blockIdx.x * 4 + (threadIdx.x >> 6);
  const int lane = threadIdx.x & 63;
  float s = 0;
  for (int k = lane; k < Hd; k += 64) s += states[(size_t)row * Hd + k] * wg[k];
  #pragma unroll
  for (int off = 32; off > 0; off >>= 1) s += __shfl_down(s, off, 64);
  if (lane == 0) gate[row] = sigmoidf_(s + bg[0]);
}

// attn + fused featb update: featb[row] += gate[row]*ms*ctx[row]
__global__ __launch_bounds__(256) void attn_kernel(
    const float* __restrict__ q, const float* __restrict__ k,
    const float* __restrict__ v, float* __restrict__ featb,
    const float* __restrict__ gate, const float* __restrict__ msp)
{
  const int row = blockIdx.x;
  const int b = row >> 11, qi = row & (Sd - 1);
  const int tid = threadIdx.x, lane = tid & 63, wv = tid >> 6;
  __shared__ float qs[MDd];
  __shared__ float sc[Wd];
  qs[tid] = q[(size_t)row * MDd + tid];
  __syncthreads();
  const int lo = (qi > Wd) ? (qi - Wd) : 0;
  const int len = qi - lo;
  const float gm = gate[row] * msp[0];
  for (int jj = wv; jj < len; jj += 4) {
    const float* kr = k + (size_t)(b * Sd + lo + jj) * MDd;
    f32x4 kv = *reinterpret_cast<const f32x4*>(kr + lane * 4);
    f32x4 qv = *reinterpret_cast<const f32x4*>(&qs[lane * 4]);
    float s = kv.x * qv.x + kv.y * qv.y + kv.z * qv.z + kv.w * qv.w;
    #pragma unroll
    for (int off = 32; off > 0; off >>= 1) s += __shfl_down(s, off, 64);
    if (lane == 0) sc[jj] = s * 0.0625f;
  }
  __syncthreads();
  if (wv == 0 && len > 0) {
    float m = -3.4e38f;
    for (int jj = lane; jj < len; jj += 64) m = fmaxf(m, sc[jj]);
    #pragma unroll
    for (int off = 32; off > 0; off >>= 1) m = fmaxf(m, __shfl_xor(m, off, 64));
    float ssum = 0;
    for (int jj = lane; jj < len; jj += 64) { float e = expf(sc[jj] - m); sc[jj] = e; ssum += e; }
    #pragma unroll
    for (int off = 32; off > 0; off >>= 1) ssum += __shfl_xor(ssum, off, 64);
    const float inv = 1.f / ssum;
    for (int jj = lane; jj < len; jj += 64) sc[jj] *= inv;
  }
  __syncthreads();
  #pragma unroll
  for (int e0 = 0; e0 < Ed; e0 += 256) {
    const int e = e0 + tid;
    float a = 0;
    for (int jj = 0; jj < len; ++jj)
      a += sc[jj] * v[(size_t)(b * Sd + lo + jj) * Ed + e];
    featb[(size_t)row * Ed + e] += gm * a;
  }
}

// ---------------------------------------------------------------------------
extern "C" void kernel_launch(void* const* d_in, const int* in_sizes, int n_in,
                              void* d_out, int out_size, void* d_ws, size_t ws_size,
                              hipStream_t stream)
{
  const int*   ids    = (const int*)d_in[0];
  const int*   untied = (const int*)d_in[1];
  const float* emb    = (const float*)d_in[2];
  const float* w_ih   = (const float*)d_in[3];
  const float* w_hh   = (const float*)d_in[4];
  const float* b_ih   = (const float*)d_in[5];
  const float* b_hh   = (const float*)d_in[6];
  const float* wq     = (const float*)d_in[7];
  const float* bq     = (const float*)d_in[8];
  const float* wk     = (const float*)d_in[9];
  const float* bk     = (const float*)d_in[10];
  const float* wv     = (const float*)d_in[11];
  const float* bv     = (const float*)d_in[12];
  const float* wg     = (const float*)d_in[13];
  const float* bg     = (const float*)d_in[14];
  const float* w_fc   = (const float*)d_in[15];
  const float* b_fc   = (const float*)d_in[16];
  const float* w_hp   = (const float*)d_in[17];
  const float* b_hp   = (const float*)d_in[18];
  const float* out_b  = (const float*)d_in[19];
  const float* w_ph   = (const float*)d_in[20];
  const float* b_ph   = (const float*)d_in[21];
  const float* msc    = (const float*)d_in[22];
  float* out = (float*)d_out;

  float* ws      = (float*)d_ws;
  float* gi      = ws;                               // [BS][3H]
  float* states  = gi + (size_t)BS * 3 * Hd;         // [BS][H]
  float* featb   = states + (size_t)BS * Hd;         // x, then base_feat [BS][E]
  float* hfb     = featb + (size_t)BS * Ed;          // hf [BS][4E], later q/k/v/gate
  unsigned long long* hb = (unsigned long long*)(hfb + (size_t)BS * 4 * Ed); // [2][2][Hd]

  float* qb    = hfb;
  float* kb    = qb + (size_t)BS * MDd;
  float* vb    = kb + (size_t)BS * MDd;
  float* gateb = vb + (size_t)BS * Ed;

  hipMemsetAsync(hb, 0, 2 * 2 * Hd * sizeof(unsigned long long), stream);

  // x = emb[ids]
  embed_kernel<<<BS, 128, 0, stream>>>(ids, emb, featb);
  // gi = x @ w_ih^T + b_ih
  gemm_bt<0><<<dim3(3 * Hd / 128, BS / 128), 256, 0, stream>>>(
      featb, w_ih, b_ih, gi, BS, 3 * Hd, Ed, 3 * Hd, nullptr, nullptr, nullptr);
  // states = GRU(gi)
  gru_kernel<<<GBLK, 1024, 0, stream>>>(gi, w_hh, b_hh, states, hb);
  // hf = relu(states @ w_fc^T + b_fc)^2
  gemm_bt<1><<<dim3(4 * Ed / 128, BS / 128), 256, 0, stream>>>(
      states, w_fc, b_fc, hfb, BS, 4 * Ed, Hd, 4 * Ed, nullptr, nullptr, nullptr);
  // base_feat = hf @ w_hp^T + b_hp
  gemm_bt<0><<<dim3(Ed / 128, BS / 128), 256, 0, stream>>>(
      hfb, w_hp, b_hp, featb, BS, Ed, 4 * Ed, Ed, nullptr, nullptr, nullptr);
  // base_logits = base_feat @ emb^T + out_bias  -> d_out
  gemm_bt<0><<<dim3(Vd / 128, BS / 128), 256, 0, stream>>>(
      featb, emb, out_b, out, BS, Vd, Ed, Vd, nullptr, nullptr, nullptr);
  // q,k,v
  gemm_bt<0><<<dim3(MDd / 128, BS / 128), 256, 0, stream>>>(
      states, wq, bq, qb, BS, MDd, Hd, MDd, nullptr, nullptr, nullptr);
  gemm_bt<0><<<dim3(MDd / 128, BS / 128), 256, 0, stream>>>(
      states, wk, bk, kb, BS, MDd, Hd, MDd, nullptr, nullptr, nullptr);
  gemm_bt<0><<<dim3(Ed / 128, BS / 128), 256, 0, stream>>>(
      states, wv, bv, vb, BS, Ed, Hd, Ed, nullptr, nullptr, nullptr);
  // gate
  gate_kernel<<<BS / 4, 256, 0, stream>>>(states, wg, bg, gateb);
  // ctx = windowed attention; featb += gate*ms*ctx fused in epilogue
  attn_kernel<<<BS, 256, 0, stream>>>(qb, kb, vb, featb, gateb, msc);
  // scatter: d_out[r, untied[c]] += fused_feat @ w_ph^T + (1+gate*ms)*b_ph
  gemm_bt<3><<<dim3(Pd / 128, BS / 128), 256, 0, stream>>>(
      featb, w_ph, b_ph, out, BS, Pd, Ed, Vd, gateb, msc, untied);
}

// Round 12
// 6540.775 us; speedup vs baseline: 1.7423x; 1.3948x over previous
//
#include <hip/hip_runtime.h>
#include <math.h>

typedef __attribute__((ext_vector_type(4))) float f32x4;
typedef __attribute__((ext_vector_type(2))) float f32x2;
typedef __attribute__((ext_vector_type(8))) __bf16 bf16x8;
typedef __attribute__((ext_vector_type(4))) __bf16 bf16x4;
typedef __attribute__((ext_vector_type(4))) unsigned int u32x4;

#define DI __device__ __forceinline__

constexpr int Bd = 2, Sd = 2048, Vd = 32000, Ed = 512, Hd = 1024, MDd = 256, Pd = 4096, Wd = 128;
constexpr int BS = Bd * Sd;          // 4096 rows
constexpr int GBLK = 128;            // GRU blocks: 64 per batch group, 1024 thr

DI float sigmoidf_(float x) { return 1.0f / (1.0f + expf(-x)); }

// ---------------------------------------------------------------------------
// Generic GEMM: C[M,N] = epi( A[M,K] * Wt[N,K]^T + bias )
// EPI 0: C = acc + bias
// EPI 1: C = (relu(acc + bias))^2
// EPI 3: atomicAdd(C[r, untied[c]], acc + (1 + gate[r]*ms) * bias[c])
// ---------------------------------------------------------------------------
template<int EPI>
__global__ __launch_bounds__(256) void gemm_bt(
    const float* __restrict__ A, const float* __restrict__ Wt,
    const float* __restrict__ bias, float* __restrict__ C,
    int M, int N, int K, int ldc,
    const float* __restrict__ gate, const float* __restrict__ msp,
    const int* __restrict__ untied)
{
  __shared__ __bf16 As[128][40];   // +8 pad: 80B row stride, 16B-aligned
  __shared__ __bf16 Bs[128][40];
  const int tid  = threadIdx.x;
  const int lane = tid & 63, wv = tid >> 6;
  const int m0 = blockIdx.y * 128, n0 = blockIdx.x * 128;
  const int wrow = (wv >> 1) * 64, wcol = (wv & 1) * 64;

  f32x4 acc[4][4] = {};

  const int sr  = tid >> 3;          // 0..31
  const int sc4 = (tid & 7) << 2;    // 0..28 step 4
  const int nk  = K >> 5;

  for (int kt = 0; kt < nk; ++kt) {
    const int k0 = kt << 5;
    __syncthreads();
    #pragma unroll
    for (int i = 0; i < 4; ++i) {
      const int r = sr + 32 * i;
      f32x4 av = *reinterpret_cast<const f32x4*>(A  + (size_t)(m0 + r) * K + k0 + sc4);
      f32x4 bv = *reinterpret_cast<const f32x4*>(Wt + (size_t)(n0 + r) * K + k0 + sc4);
      bf16x4 ah, bh;
      ah.x = (__bf16)av.x; ah.y = (__bf16)av.y; ah.z = (__bf16)av.z; ah.w = (__bf16)av.w;
      bh.x = (__bf16)bv.x; bh.y = (__bf16)bv.y; bh.z = (__bf16)bv.z; bh.w = (__bf16)bv.w;
      *reinterpret_cast<bf16x4*>(&As[r][sc4]) = ah;
      *reinterpret_cast<bf16x4*>(&Bs[r][sc4]) = bh;
    }
    __syncthreads();

    bf16x8 af[4], bfr[4];
    #pragma unroll
    for (int t2 = 0; t2 < 4; ++t2) {
      af[t2]  = *reinterpret_cast<const bf16x8*>(&As[wrow + t2 * 16 + (lane & 15)][(lane >> 4) * 8]);
      bfr[t2] = *reinterpret_cast<const bf16x8*>(&Bs[wcol + t2 * 16 + (lane & 15)][(lane >> 4) * 8]);
    }
    #pragma unroll
    for (int mi = 0; mi < 4; ++mi)
      #pragma unroll
      for (int ni = 0; ni < 4; ++ni)
        acc[mi][ni] = __builtin_amdgcn_mfma_f32_16x16x32_bf16(af[mi], bfr[ni], acc[mi][ni], 0, 0, 0);
  }

  const float ms = (EPI == 3) ? msp[0] : 0.f;
  #pragma unroll
  for (int mi = 0; mi < 4; ++mi) {
    #pragma unroll
    for (int ni = 0; ni < 4; ++ni) {
      const int cc = n0 + wcol + ni * 16 + (lane & 15);
      const float bv = bias ? bias[cc] : 0.f;
      #pragma unroll
      for (int rg = 0; rg < 4; ++rg) {
        const int rr = m0 + wrow + mi * 16 + (lane >> 4) * 4 + rg;
        const float v = acc[mi][ni][rg];
        if (EPI == 0) {
          C[(size_t)rr * ldc + cc] = v + bv;
        } else if (EPI == 1) {
          float u = fmaxf(v + bv, 0.f);
          C[(size_t)rr * ldc + cc] = u * u;
        } else {
          float g = 1.f + gate[rr] * ms;
          atomicAdd(&C[(size_t)rr * ldc + untied[cc]], v + g * bv);
        }
      }
    }
  }
}

// Device-coherent 16B poll: sc0 (L1 bypass) + sc1 (L2 bypass) reads the
// coherence point where producers' relaxed agent atomic stores land.
DI void poll2_coherent(const unsigned long long* p, u32x4& a) {
  asm volatile("global_load_dwordx4 %0, %1, off sc0 sc1\n\t"
               "s_waitcnt vmcnt(0)"
               : "=&v"(a) : "v"(p) : "memory");
}

// ---------------------------------------------------------------------------
// Persistent GRU v13 = v11 + COALESCED PUBLISH. 128 blocks x 1024 threads,
// two independent groups of 64 (one per batch); wave wv of group-block gb
// owns ONE h-index j = gb*16+wv (3 w_hh rows in registers, 3 dot-1024s).
// v11's publish was 16 separate lane-0 8B stores per block -> 8 serialized
// partial-line RMWs per 64B line at the coherence point (WRITE_SIZE 147MB
// for 48MB payload). v13: all lanes hold h after the broadcast gate; lane 0
// of each wave stages h to LDS; barrier (also enforces all-hsm-reads-done);
// lanes 0-15 of wave 0 store the block's 16 tagged u64 slots as ONE wave
// instruction -> 2 full-line writes. 16x fewer publish ops, no partial-line
// serialization. Poll/rotation/fallback identical to v11.
// ---------------------------------------------------------------------------
__global__ __launch_bounds__(1024) void gru_kernel(
    const float* __restrict__ gi,    // [BS][3H]
    const float* __restrict__ w_hh,  // [3H][H]
    const float* __restrict__ b_hh,  // [3H]
    float* __restrict__ states,      // [BS][H]
    unsigned long long* __restrict__ hb)  // [2 parity][2 batch][Hd] {tag,val}
{
  __shared__ float hsm[Hd];          // this batch's h(t-1)
  __shared__ float gpre_sm[2][48];   // parity-buffered pregates for 16 h-idx
  __shared__ float pubst[16];        // publish staging: block's 16 h values
  const int bid = blockIdx.x, tid = threadIdx.x;
  const int lane = tid & 63, wv = tid >> 6;
  const int b  = bid >> 6;           // batch group
  const int gb = bid & 63;           // block index within group
  const int j  = gb * 16 + wv;       // this wave's h index

  // --- w_hh rows (r,z,n for j) into registers, lane-sliced (16 floats ea) ---
  f32x4 wr[4], wz[4], wn[4];
  #pragma unroll
  for (int c = 0; c < 4; ++c) {
    const int k = lane * 4 + c * 256;
    wr[c] = *reinterpret_cast<const f32x4*>(w_hh + (size_t)(0 * Hd + j) * Hd + k);
    wz[c] = *reinterpret_cast<const f32x4*>(w_hh + (size_t)(1 * Hd + j) * Hd + k);
    wn[c] = *reinterpret_cast<const f32x4*>(w_hh + (size_t)(2 * Hd + j) * Hd + k);
  }
  const float br = b_hh[j], bz = b_hh[Hd + j], bn = b_hh[2 * Hd + j];

  for (int i = tid; i < Hd; i += 1024) hsm[i] = 0.f;
  if (tid < 48) {
    const int g = tid >> 4, o = tid & 15;
    gpre_sm[0][tid] = gi[(size_t)b * Sd * 3 * Hd + g * Hd + gb * 16 + o];
  }
  __syncthreads();

  // rotated slot pair: staggers each block's L3 sweep; gb==0 -> rotation 0
  const int slot0 = (((tid & 511) + (gb << 3)) & 511) * 2;
  const bool poller = (tid < 512);
  const bool writer = (gb == 0);

  for (int t = 0; t < Sd; ++t) {
    // ---- matvec: 3 dot-1024 per wave, weights in regs, h from LDS ----
    float d0 = 0, d1 = 0, d2 = 0;
    #pragma unroll
    for (int c = 0; c < 4; ++c) {
      f32x4 hv = *reinterpret_cast<const f32x4*>(&hsm[lane * 4 + c * 256]);
      d0 += wr[c].x*hv.x + wr[c].y*hv.y + wr[c].z*hv.z + wr[c].w*hv.w;
      d1 += wz[c].x*hv.x + wz[c].y*hv.y + wz[c].z*hv.z + wz[c].w*hv.w;
      d2 += wn[c].x*hv.x + wn[c].y*hv.y + wn[c].z*hv.z + wn[c].w*hv.w;
    }
    #pragma unroll
    for (int off = 32; off > 0; off >>= 1) {
      d0 += __shfl_xor(d0, off, 64);
      d1 += __shfl_xor(d1, off, 64);
      d2 += __shfl_xor(d2, off, 64);
    }

    const unsigned tagu = (unsigned)(t + 1);
    const unsigned long long tag = (unsigned long long)(t + 1);
    const int par = (t + 1) & 1;
    unsigned long long* hbp = hb + ((size_t)par * 2 + b) * Hd;

    // ---- gate: wave-parallel (lanes 0/1 sigmoids concurrent, tanh bcast) ----
    const float pgr = gpre_sm[t & 1][wv];
    const float pgz = gpre_sm[t & 1][16 + wv];
    const float pgn = gpre_sm[t & 1][32 + wv];
    const float a  = (lane == 0) ? (pgr + d0 + br) : (pgz + d1 + bz);
    const float sg = sigmoidf_(a);
    const float r  = __shfl(sg, 0, 64);
    const float z  = __shfl(sg, 1, 64);
    const float n  = tanhf(pgn + r * (d2 + bn));
    const float ho = hsm[j];
    const float h  = (1.f - z) * n + z * ho;
    if (lane == 0) pubst[wv] = h;

    // barrier 1: pubst ready AND every wave has finished reading hsm
    __syncthreads();

    // ---- coalesced publish: wave 0 lanes 0-15, one instruction,
    //      16 consecutive u64 -> 2 full 64B-line writes ----
    if (tid < 16) {
      const float hv = pubst[tid];
      __hip_atomic_store(&hbp[gb * 16 + tid],
                         (tag << 32) | (unsigned long long)__float_as_uint(hv),
                         __ATOMIC_RELAXED, __HIP_MEMORY_SCOPE_AGENT);
    }

    // ---- coalesced gi prefetch for t+1 into the other parity buffer ----
    if (tid >= 64 && tid < 112) {
      const int q = tid - 64;
      const int g = q >> 4, o = q & 15;
      const int tn = (t + 1 < Sd) ? (t + 1) : t;
      gpre_sm[par][q] = gi[((size_t)b * Sd + tn) * 3 * Hd + g * Hd + gb * 16 + o];
    }

    if (poller && (t + 1 < Sd || writer)) {
      // ---- poll own-batch slots: one 16B device-coherent load per poller ----
      float v0 = 0, v1 = 0;
      bool done = false;
      for (int rounds = 0; rounds < 16384 && !done; ++rounds) {
        u32x4 a4;
        poll2_coherent(&hbp[slot0], a4);
        if (a4[1] == tagu && a4[3] == tagu) {
          v0 = __uint_as_float(a4[0]); v1 = __uint_as_float(a4[2]);
          done = true;
        } else if (rounds >= 6) {
          __builtin_amdgcn_s_sleep(1);   // pace stragglers
        }
      }
      if (!done) {
        // guaranteed-progress fallback: 8B atomic loads (proven path)
        bool f0 = false, f1 = false;
        do {
          unsigned long long x0, x1;
          if (!f0) x0 = __hip_atomic_load(&hbp[slot0 + 0], __ATOMIC_RELAXED, __HIP_MEMORY_SCOPE_AGENT);
          if (!f1) x1 = __hip_atomic_load(&hbp[slot0 + 1], __ATOMIC_RELAXED, __HIP_MEMORY_SCOPE_AGENT);
          if (!f0 && (x0 >> 32) == tag) { v0 = __uint_as_float((unsigned)x0); f0 = true; }
          if (!f1 && (x1 >> 32) == tag) { v1 = __uint_as_float((unsigned)x1); f1 = true; }
        } while (!(f0 && f1));
      }
      if (writer) {
        f32x2 sv; sv.x = v0; sv.y = v1;
        *reinterpret_cast<f32x2*>(states + ((size_t)b * Sd + t) * Hd + slot0) = sv;
      }
      hsm[slot0]     = v0;
      hsm[slot0 + 1] = v1;
    }
    __syncthreads();   // hsm fully updated before next matvec
  }
}

// ---------------------------------------------------------------------------
__global__ __launch_bounds__(128) void embed_kernel(
    const int* __restrict__ ids, const float* __restrict__ emb, float* __restrict__ x)
{
  const int row = blockIdx.x;
  const int tok = ids[row];
  reinterpret_cast<f32x4*>(x)[(size_t)row * (Ed / 4) + threadIdx.x] =
      reinterpret_cast<const f32x4*>(emb)[(size_t)tok * (Ed / 4) + threadIdx.x];
}

__global__ __launch_bounds__(256) void gate_kernel(
    const float* __restrict__ states, const float* __restrict__ wg,
    const float* __restrict__ bg, float* __restrict__ gate)
{
  const int row = blockIdx.x * 4 + (threadIdx.x >> 6);
  const int lane = threadIdx.x & 63;
  float s = 0;
  for (int k = lane; k < Hd; k += 64) s += states[(size_t)row * Hd + k] * wg[k];
  #pragma unroll
  for (int off = 32; off > 0; off >>= 1) s += __shfl_down(s, off, 64);
  if (lane == 0) gate[row] = sigmoidf_(s + bg[0]);
}

// attn + fused featb update: featb[row] += gate[row]*ms*ctx[row]
__global__ __launch_bounds__(256) void attn_kernel(
    const float* __restrict__ q, const float* __restrict__ k,
    const float* __restrict__ v, float* __restrict__ featb,
    const float* __restrict__ gate, const float* __restrict__ msp)
{
  const int row = blockIdx.x;
  const int b = row >> 11, qi = row & (Sd - 1);
  const int tid = threadIdx.x, lane = tid & 63, wv = tid >> 6;
  __shared__ float qs[MDd];
  __shared__ float sc[Wd];
  qs[tid] = q[(size_t)row * MDd + tid];
  __syncthreads();
  const int lo = (qi > Wd) ? (qi - Wd) : 0;
  const int len = qi - lo;
  const float gm = gate[row] * msp[0];
  for (int jj = wv; jj < len; jj += 4) {
    const float* kr = k + (size_t)(b * Sd + lo + jj) * MDd;
    f32x4 kv = *reinterpret_cast<const f32x4*>(kr + lane * 4);
    f32x4 qv = *reinterpret_cast<const f32x4*>(&qs[lane * 4]);
    float s = kv.x * qv.x + kv.y * qv.y + kv.z * qv.z + kv.w * qv.w;
    #pragma unroll
    for (int off = 32; off > 0; off >>= 1) s += __shfl_down(s, off, 64);
    if (lane == 0) sc[jj] = s * 0.0625f;
  }
  __syncthreads();
  if (wv == 0 && len > 0) {
    float m = -3.4e38f;
    for (int jj = lane; jj < len; jj += 64) m = fmaxf(m, sc[jj]);
    #pragma unroll
    for (int off = 32; off > 0; off >>= 1) m = fmaxf(m, __shfl_xor(m, off, 64));
    float ssum = 0;
    for (int jj = lane; jj < len; jj += 64) { float e = expf(sc[jj] - m); sc[jj] = e; ssum += e; }
    #pragma unroll
    for (int off = 32; off > 0; off >>= 1) ssum += __shfl_xor(ssum, off, 64);
    const float inv = 1.f / ssum;
    for (int jj = lane; jj < len; jj += 64) sc[jj] *= inv;
  }
  __syncthreads();
  #pragma unroll
  for (int e0 = 0; e0 < Ed; e0 += 256) {
    const int e = e0 + tid;
    float a = 0;
    for (int jj = 0; jj < len; ++jj)
      a += sc[jj] * v[(size_t)(b * Sd + lo + jj) * Ed + e];
    featb[(size_t)row * Ed + e] += gm * a;
  }
}

// ---------------------------------------------------------------------------
extern "C" void kernel_launch(void* const* d_in, const int* in_sizes, int n_in,
                              void* d_out, int out_size, void* d_ws, size_t ws_size,
                              hipStream_t stream)
{
  const int*   ids    = (const int*)d_in[0];
  const int*   untied = (const int*)d_in[1];
  const float* emb    = (const float*)d_in[2];
  const float* w_ih   = (const float*)d_in[3];
  const float* w_hh   = (const float*)d_in[4];
  const float* b_ih   = (const float*)d_in[5];
  const float* b_hh   = (const float*)d_in[6];
  const float* wq     = (const float*)d_in[7];
  const float* bq     = (const float*)d_in[8];
  const float* wk     = (const float*)d_in[9];
  const float* bk     = (const float*)d_in[10];
  const float* wv     = (const float*)d_in[11];
  const float* bv     = (const float*)d_in[12];
  const float* wg     = (const float*)d_in[13];
  const float* bg     = (const float*)d_in[14];
  const float* w_fc   = (const float*)d_in[15];
  const float* b_fc   = (const float*)d_in[16];
  const float* w_hp   = (const float*)d_in[17];
  const float* b_hp   = (const float*)d_in[18];
  const float* out_b  = (const float*)d_in[19];
  const float* w_ph   = (const float*)d_in[20];
  const float* b_ph   = (const float*)d_in[21];
  const float* msc    = (const float*)d_in[22];
  float* out = (float*)d_out;

  float* ws      = (float*)d_ws;
  float* gi      = ws;                               // [BS][3H]
  float* states  = gi + (size_t)BS * 3 * Hd;         // [BS][H]
  float* featb   = states + (size_t)BS * Hd;         // x, then base_feat [BS][E]
  float* hfb     = featb + (size_t)BS * Ed;          // hf [BS][4E], later q/k/v/gate
  unsigned long long* hb = (unsigned long long*)(hfb + (size_t)BS * 4 * Ed); // [2][2][Hd]

  float* qb    = hfb;
  float* kb    = qb + (size_t)BS * MDd;
  float* vb    = kb + (size_t)BS * MDd;
  float* gateb = vb + (size_t)BS * Ed;

  hipMemsetAsync(hb, 0, 2 * 2 * Hd * sizeof(unsigned long long), stream);

  // x = emb[ids]
  embed_kernel<<<BS, 128, 0, stream>>>(ids, emb, featb);
  // gi = x @ w_ih^T + b_ih
  gemm_bt<0><<<dim3(3 * Hd / 128, BS / 128), 256, 0, stream>>>(
      featb, w_ih, b_ih, gi, BS, 3 * Hd, Ed, 3 * Hd, nullptr, nullptr, nullptr);
  // states = GRU(gi)
  gru_kernel<<<GBLK, 1024, 0, stream>>>(gi, w_hh, b_hh, states, hb);
  // hf = relu(states @ w_fc^T + b_fc)^2
  gemm_bt<1><<<dim3(4 * Ed / 128, BS / 128), 256, 0, stream>>>(
      states, w_fc, b_fc, hfb, BS, 4 * Ed, Hd, 4 * Ed, nullptr, nullptr, nullptr);
  // base_feat = hf @ w_hp^T + b_hp
  gemm_bt<0><<<dim3(Ed / 128, BS / 128), 256, 0, stream>>>(
      hfb, w_hp, b_hp, featb, BS, Ed, 4 * Ed, Ed, nullptr, nullptr, nullptr);
  // base_logits = base_feat @ emb^T + out_bias  -> d_out
  gemm_bt<0><<<dim3(Vd / 128, BS / 128), 256, 0, stream>>>(
      featb, emb, out_b, out, BS, Vd, Ed, Vd, nullptr, nullptr, nullptr);
  // q,k,v
  gemm_bt<0><<<dim3(MDd / 128, BS / 128), 256, 0, stream>>>(
      states, wq, bq, qb, BS, MDd, Hd, MDd, nullptr, nullptr, nullptr);
  gemm_bt<0><<<dim3(MDd / 128, BS / 128), 256, 0, stream>>>(
      states, wk, bk, kb, BS, MDd, Hd, MDd, nullptr, nullptr, nullptr);
  gemm_bt<0><<<dim3(Ed / 128, BS / 128), 256, 0, stream>>>(
      states, wv, bv, vb, BS, Ed, Hd, Ed, nullptr, nullptr, nullptr);
  // gate
  gate_kernel<<<BS / 4, 256, 0, stream>>>(states, wg, bg, gateb);
  // ctx = windowed attention; featb += gate*ms*ctx fused in epilogue
  attn_kernel<<<BS, 256, 0, stream>>>(qb, kb, vb, featb, gateb, msc);
  // scatter: d_out[r, untied[c]] += fused_feat @ w_ph^T + (1+gate*ms)*b_ph
  gemm_bt<3><<<dim3(Pd / 128, BS / 128), 256, 0, stream>>>(
      featb, w_ph, b_ph, out, BS, Pd, Ed, Vd, gateb, msc, untied);
}